// Round 14
// baseline (1138.290 us; speedup 1.0000x reference)
//
#include <hip/hip_runtime.h>

// ---------------------------------------------------------------------------
// Transolver forward, MI355X. Round 14: R13 + deslice folded into out-proj:
//  - attn epilogue computes OW[b][c][h*64+g] = os @ out_w^T via one K=32 MFMA
//    pass (bf16, stored in free XM region)
//  - gemm_desl_ln: K=512 gemm_ln variant, A = SW gathered per-head (kc<->h),
//    B = OW per batch; + residual + LN2. Deletes 5 deslice dispatches and the
//    OX round-trip (-32MB/layer).
// ---------------------------------------------------------------------------

#define MTOK 32768   // B*N
#define NB   16384   // N

typedef unsigned short u16;
using short8 = __attribute__((ext_vector_type(8))) short;
using f4     = __attribute__((ext_vector_type(4))) float;

__device__ __forceinline__ float bfu(u16 u) {
    return __uint_as_float(((unsigned)u) << 16);
}
__device__ __forceinline__ u16 f2bf(float f) {
    unsigned u = __float_as_uint(f);
    u += 0x7FFFu + ((u >> 16) & 1u);   // round-to-nearest-even
    return (u16)(u >> 16);
}
__device__ __forceinline__ float ldf(const void* p, int i, int isbf) {
    return isbf ? bfu(((const u16*)p)[i]) : ((const float*)p)[i];
}
__device__ __forceinline__ float4 dec4(ushort4 u) {
    return make_float4(bfu(u.x), bfu(u.y), bfu(u.z), bfu(u.w));
}
__device__ __forceinline__ float gelu_f(float x) {
    return 0.5f * x * (1.0f + erff(x * 0.7071067811865475f));
}

typedef __attribute__((address_space(1))) const unsigned int* as1p;
typedef __attribute__((address_space(3))) unsigned int* as3p;
__device__ __forceinline__ void gload_lds16(const u16* g, u16* l) {
    __builtin_amdgcn_global_load_lds((as1p)g, (as3p)l, 16, 0, 0);
}

// ---------------- workspace layout -----------------------------------------
#define F_H      ((size_t)0)          // u16 H [32768,256] (in fp32 slot)
#define F_OS     ((size_t)8388608)    // (unused now)
#define F_TOKP   ((size_t)8421376)    // [64ch,16bh,2048]
#define F_NORMP  ((size_t)10518528)   // [64ch,16bh,64]
#define F_TOK    ((size_t)10584064)   // [16,2048]
#define F_NORM   ((size_t)10616832)   // [16,64]
#define F_BIAS   ((size_t)10617856)
#define F_PARAMS ((size_t)10626048)   // fp32 small params (232836)
#define F_BF     ((size_t)10858884)   // u16 region base (byte off %16 == 0)
// bias-internal (floats, rel to F_BIAS)
#define B_PB2C 0        // 256
#define B_OUTB 256      // 1280
#define B_M1B  1536     // 1280
#define B_M2B  2816     // 1280
#define B_HB1  4096     // 256
#define B_SP   4352     // [5][768]: 0..511 folded slice bias, 512..767 pfx_b
#define B_END  8192
// u16 region offsets
#define U_WT     ((size_t)0)
#define WT_PRE2  0                   // [256][512]
#define WT_HEAD1 131072              // [256][256]
#define WT_SPFX  196608              // 5 x [768][256]: rows 0..511 pxsl, 512..767 pfx
#define WT_OUT   1179648             // 5 x [256][256]
#define WT_MLP1  1507328
#define WT_MLP2  1835008
#define WT_END   2162688
#define U_Y   ((size_t)2162688)      // [32768,256] bf16
#define U_XM  ((size_t)10551296)     // [32768,256]; HID prologue; OW [2][256][512] in loop
#define U_FM  ((size_t)18939904)
#define U_SW  ((size_t)27328512)     // [16,16384,64]
// total ws: 10858884*4 + 44105728*2 = 131,646,992 B (~125.6 MB)

// params-internal offsets (floats, rel to F_PARAMS)
#define P_X    0
#define P_FX   65536
#define P_W1   196608
#define P_B1   199680
#define P_LN1G 200192
#define P_LN1B 201472
#define P_LN2G 202752
#define P_LN2B 204032
#define P_LN3G 205312
#define P_LN3B 205568
#define P_SLW  205824
#define P_SLB  216064
#define P_TEMP 216384
#define P_QW   216448
#define P_KW   221568
#define P_VW   226688
#define P_HW2  231808
#define P_HB2  232832
#define P_END  232836

// ---------------- cvt: small params -> fp32 params region ------------------
__global__ __launch_bounds__(256) void cvt_kernel(
    const void* x, const void* fx, const void* w1, const void* b1,
    const void* l1g, const void* l1b, const void* l2g, const void* l2b,
    const void* l3g, const void* l3b, const void* slw, const void* slb,
    const void* tmp, const void* qw, const void* kw, const void* vw,
    const void* hw2, const void* hb2, float* __restrict__ P)
{
    int isbf = (((const u16*)tmp)[0] != 0);
    int idx = blockIdx.x * 256 + threadIdx.x;
    const void* s; int o;
    if      (idx < 65536)  { s = x;   o = idx; }
    else if (idx < 196608) { s = fx;  o = idx - 65536; }
    else if (idx < 199680) { s = w1;  o = idx - 196608; }
    else if (idx < 200192) { s = b1;  o = idx - 199680; }
    else if (idx < 201472) { s = l1g; o = idx - 200192; }
    else if (idx < 202752) { s = l1b; o = idx - 201472; }
    else if (idx < 204032) { s = l2g; o = idx - 202752; }
    else if (idx < 205312) { s = l2b; o = idx - 204032; }
    else if (idx < 205568) { s = l3g; o = idx - 205312; }
    else if (idx < 205824) { s = l3b; o = idx - 205568; }
    else if (idx < 216064) { s = slw; o = idx - 205824; }
    else if (idx < 216384) { s = slb; o = idx - 216064; }
    else if (idx < 216424) { s = tmp; o = idx - 216384; }
    else if (idx < 216448) { return; }
    else if (idx < 221568) { s = qw;  o = idx - 216448; }
    else if (idx < 226688) { s = kw;  o = idx - 221568; }
    else if (idx < 231808) { s = vw;  o = idx - 226688; }
    else if (idx < 232832) { s = hw2; o = idx - 231808; }
    else if (idx < 232836) { s = hb2; o = idx - 232832; }
    else return;
    P[idx] = ldf(s, o, isbf);
}

// ---------------- prep_main: LDS-tiled transpose -> bf16 [N][K]; biases ----
__global__ __launch_bounds__(256) void prep_main(
    const void* pre_w2, const void* head_w1, const void* pfx_w,
    const void* out_w, const void* mlp_w1, const void* mlp_w2,
    const void* pre_b2, const void* placeholder, const void* pfx_b,
    const void* out_b, const void* mlp_b1, const void* mlp_b2,
    const void* head_b1, const void* tmp,
    u16* __restrict__ WT, float* __restrict__ BIAS)
{
    int isbf = (((const u16*)tmp)[0] != 0);
    int blk = blockIdx.x;
    int t = threadIdx.x;
    if (blk < 368) {
        __shared__ float tile[64][65];
        const void* src; size_t srcoff; size_t dbase; int dstride;
        int k0, n0;
        if (blk < 32) {                       // pre_w2 [512,256] -> [256][512]
            int tk = blk >> 2, tn = blk & 3;
            src = pre_w2; srcoff = 0;
            k0 = tk * 64; n0 = tn * 64;
            dbase = WT_PRE2; dstride = 512;
        } else {
            int m = (blk - 32) >> 4, tl = (blk - 32) & 15;
            int tk = tl >> 2, tn = tl & 3;
            k0 = tk * 64; n0 = tn * 64; dstride = 256;
            if (m == 0)       { src = head_w1; srcoff = 0;               dbase = WT_HEAD1; }
            else if (m <= 5)  { int i = m - 1;  src = pfx_w;  srcoff = (size_t)i * 65536;
                                dbase = WT_SPFX + (size_t)i * 196608 + (size_t)512 * 256; }
            else if (m <= 10) { int i = m - 6;  src = out_w;  srcoff = (size_t)i * 65536;
                                dbase = WT_OUT + (size_t)i * 65536; }
            else if (m <= 15) { int i = m - 11; src = mlp_w1; srcoff = (size_t)i * 65536;
                                dbase = WT_MLP1 + (size_t)i * 65536; }
            else              { int i = m - 16; src = mlp_w2; srcoff = (size_t)i * 65536;
                                dbase = WT_MLP2 + (size_t)i * 65536; }
        }
#pragma unroll
        for (int p = 0; p < 16; ++p) {
            int flat = t + 256 * p;
            int r = flat >> 6, c = flat & 63;
            tile[r][c] = ldf(src, srcoff + (size_t)(k0 + r) * 256 + n0 + c, isbf);
        }
        __syncthreads();
#pragma unroll
        for (int p = 0; p < 16; ++p) {
            int flat = t + 256 * p;
            int r = flat >> 6, c = flat & 63;
            WT[dbase + (size_t)(n0 + r) * dstride + k0 + c] = f2bf(tile[c][r]);
        }
    } else {
        int idx = (blk - 368) * 256 + t;      // 0..5631
        if (idx < 256) {
            BIAS[B_PB2C + idx] = ldf(pre_b2, idx, isbf) + ldf(placeholder, idx, isbf);
        } else if (idx < 1536) {
            int o = idx - 256;  BIAS[B_OUTB + o] = ldf(out_b, o, isbf);
        } else if (idx < 2816) {
            int o = idx - 1536; BIAS[B_M1B + o] = ldf(mlp_b1, o, isbf);
        } else if (idx < 4096) {
            int o = idx - 2816; BIAS[B_M2B + o] = ldf(mlp_b2, o, isbf);
        } else if (idx < 4352) {
            int o = idx - 4096; BIAS[B_HB1 + o] = ldf(head_b1, o, isbf);
        } else if (idx < 5632) {
            int o = idx - 4352;
            int i = o >> 8, c = o & 255;
            BIAS[B_SP + i * 768 + 512 + c] = ldf(pfx_b, o, isbf);
        }
    }
}

// ---------------- prep_pxsl: tiled fold px_w@slice_w -> spfx rows 0..511 ---
__global__ __launch_bounds__(256) void prep_pxsl(
    const void* px_w, const void* px_b, const void* slw, const void* slb,
    const void* tmp, u16* __restrict__ WT, float* __restrict__ BIAS)
{
    int isbf = (((const u16*)tmp)[0] != 0);
    __shared__ float pxs[64 * 33];
    __shared__ float sls[2048];
    int blk = blockIdx.x;
    int i = blk >> 5, h = (blk >> 2) & 7, kb = blk & 3;
    int t = threadIdx.x;
#pragma unroll
    for (int p = 0; p < 8; ++p) {
        int flat = t + 256 * p;
        sls[flat] = ldf(slw, i * 2048 + flat, isbf);
        int k = flat >> 5, d = flat & 31;
        pxs[k * 33 + d] = ldf(px_w, i * 65536 + (kb * 64 + k) * 256 + h * 32 + d, isbf);
    }
    __syncthreads();
    int k = t & 63, gb = t >> 6;
    float acc[16];
#pragma unroll
    for (int gi = 0; gi < 16; ++gi) acc[gi] = 0.f;
#pragma unroll
    for (int d = 0; d < 32; ++d) {
        float pv = pxs[k * 33 + d];
        const float* sp = sls + d * 64 + gb * 16;
#pragma unroll
        for (int gi = 0; gi < 16; ++gi) acc[gi] = fmaf(pv, sp[gi], acc[gi]);
    }
    u16* WTp = WT + WT_SPFX + (size_t)i * 196608;
#pragma unroll
    for (int gi = 0; gi < 16; ++gi) {
        int n = h * 64 + gb * 16 + gi;
        WTp[n * 256 + kb * 64 + k] = f2bf(acc[gi]);
    }
    if (kb == 0 && t < 64) {
        int g = t;
        float a = ldf(slb, i * 64 + g, isbf);
#pragma unroll
        for (int d = 0; d < 32; ++d)
            a = fmaf(ldf(px_b, i * 256 + h * 32 + d, isbf), sls[d * 64 + g], a);
        BIAS[B_SP + i * 768 + h * 64 + g] = a;
    }
}

// ---------------- pre1: gelu(in6 @ pre_w1 + b1) -> bf16, conflict-free -----
__global__ __launch_bounds__(256) void pre1_kernel(
    const float* __restrict__ P, u16* __restrict__ HID)
{
    __shared__ float w1s[3072];
    __shared__ float b1s[512];
    int t = threadIdx.x;
#pragma unroll
    for (int p = 0; p < 12; ++p) w1s[t + 256 * p] = P[P_W1 + t + 256 * p];
    b1s[t] = P[P_B1 + t];
    b1s[t + 256] = P[P_B1 + t + 256];
    __syncthreads();
    int m = blockIdx.x * 4 + (t >> 6);
    int lane = t & 63;
    float xa = P[P_X + m * 2],      xb = P[P_X + m * 2 + 1];
    float fa = P[P_FX + m * 4],     fb = P[P_FX + m * 4 + 1];
    float fc = P[P_FX + m * 4 + 2], fd = P[P_FX + m * 4 + 3];
    size_t base = (size_t)m * 512 + lane;
#pragma unroll
    for (int jj = 0; jj < 8; ++jj) {
        int j = lane + 64 * jj;   // bank = lane%32 -> 2-way (free)
        float a = b1s[j];
        a = fmaf(xa, w1s[j], a);
        a = fmaf(xb, w1s[512 + j], a);
        a = fmaf(fa, w1s[1024 + j], a);
        a = fmaf(fb, w1s[1536 + j], a);
        a = fmaf(fc, w1s[2048 + j], a);
        a = fmaf(fd, w1s[2560 + j], a);
        HID[base + 64 * jj] = f2bf(gelu_f(a));
    }
}

// ---------------- LN-fused producer GEMM: 64x256, LDS-staged ---------------
template <int KK, bool RES>
__global__ __launch_bounds__(256, 3) void gemm_ln(
    const u16* __restrict__ A, const u16* __restrict__ Wt,
    const float* __restrict__ bias, const float* __restrict__ lng,
    const float* __restrict__ lnb, u16* __restrict__ Hb, u16* __restrict__ Y)
{
    __shared__ u16 As[64 * 64];
    __shared__ u16 Bs[256 * 64];
    __shared__ float rs2[2][64], rq2[2][64];
    const int t = threadIdx.x;
    const int wave = t >> 6, lane = t & 63;
    const int quad = lane >> 4, l15 = lane & 15;
    const int m0 = blockIdx.x * 64;
    const int wm = (wave & 1) * 32, wn = (wave >> 1) * 128;
    const int lrow = lane >> 3, ls = lane & 7;
    f4 acc[2][8];
#pragma unroll
    for (int i = 0; i < 2; ++i)
#pragma unroll
        for (int j = 0; j < 8; ++j) acc[i][j] = (f4){0.f, 0.f, 0.f, 0.f};

    for (int kc = 0; kc < KK; kc += 64) {
        if (kc) __syncthreads();
#pragma unroll
        for (int q = 0; q < 10; ++q) {
            int gr = wave * 80 + q * 8;
            if (gr < 64) {
                int row = gr + lrow;
                int chunk = ls ^ lrow;
                gload_lds16(A + (size_t)(m0 + row) * KK + kc + chunk * 8,
                            As + gr * 64);
            } else {
                int brow = gr - 64 + lrow;
                int chunk = ls ^ lrow;
                gload_lds16(Wt + (size_t)brow * KK + kc + chunk * 8,
                            Bs + (gr - 64) * 64);
            }
        }
        __syncthreads();
#pragma unroll
        for (int kk = 0; kk < 2; ++kk) {
            short8 a[2], b[8];
#pragma unroll
            for (int i = 0; i < 2; ++i) {
                int R = wm + i * 16 + l15;
                a[i] = *(const short8*)(As + R * 64 + (((quad + kk * 4) ^ (R & 7)) << 3));
            }
#pragma unroll
            for (int j = 0; j < 8; ++j) {
                int Rb = wn + j * 16 + l15;
                b[j] = *(const short8*)(Bs + Rb * 64 + (((quad + kk * 4) ^ (Rb & 7)) << 3));
            }
#pragma unroll
            for (int i = 0; i < 2; ++i)
#pragma unroll
                for (int j = 0; j < 8; ++j)
                    acc[i][j] = __builtin_amdgcn_mfma_f32_16x16x32_bf16(
                        a[i], b[j], acc[i][j], 0, 0, 0);
        }
    }
    int colj[8];
    float bj[8];
#pragma unroll
    for (int j = 0; j < 8; ++j) { colj[j] = wn + j * 16 + l15; bj[j] = bias[colj[j]]; }
    const int half = wn >> 7;
#pragma unroll
    for (int i = 0; i < 2; ++i) {
#pragma unroll
        for (int r = 0; r < 4; ++r) {
            int row = wm + i * 16 + quad * 4 + r;
            size_t gbase = (size_t)(m0 + row) * 256;
            float s = 0.f, q2 = 0.f;
#pragma unroll
            for (int j = 0; j < 8; ++j) {
                float v = acc[i][j][r] + bj[j];
                if (RES) v += bfu(Hb[gbase + colj[j]]);
                Hb[gbase + colj[j]] = f2bf(v);
                acc[i][j][r] = v;
                s += v; q2 += v * v;
            }
#pragma unroll
            for (int o = 1; o < 16; o <<= 1) { s += __shfl_xor(s, o); q2 += __shfl_xor(q2, o); }
            if (l15 == 0) { rs2[half][row] = s; rq2[half][row] = q2; }
        }
    }
    __syncthreads();
    float gj[8], betj[8];
#pragma unroll
    for (int j = 0; j < 8; ++j) { gj[j] = lng[colj[j]]; betj[j] = lnb[colj[j]]; }
#pragma unroll
    for (int i = 0; i < 2; ++i) {
#pragma unroll
        for (int r = 0; r < 4; ++r) {
            int row = wm + i * 16 + quad * 4 + r;
            size_t gbase = (size_t)(m0 + row) * 256;
            float mean = (rs2[0][row] + rs2[1][row]) * (1.0f / 256.0f);
            float var = (rq2[0][row] + rq2[1][row]) * (1.0f / 256.0f) - mean * mean;
            float rstd = rsqrtf(var + 1e-5f);
#pragma unroll
            for (int j = 0; j < 8; ++j) {
                float y = (acc[i][j][r] - mean) * rstd * gj[j] + betj[j];
                Y[gbase + colj[j]] = f2bf(y);
            }
        }
    }
}

// ---------------- deslice+out-proj fused GEMM: K=512, A=SW gather ----------
// C[m][c] = sum_{h,g} SW[(b*8+h)*NB+n][g] * OW[b][c][h*64+g] + out_b (+H) ->LN
__global__ __launch_bounds__(256, 3) void gemm_desl_ln(
    const u16* __restrict__ SW, const u16* __restrict__ OW,
    const float* __restrict__ bias, const float* __restrict__ lng,
    const float* __restrict__ lnb, u16* __restrict__ Hb, u16* __restrict__ Y)
{
    __shared__ u16 As[64 * 64];
    __shared__ u16 Bs[256 * 64];
    __shared__ float rs2[2][64], rq2[2][64];
    const int t = threadIdx.x;
    const int wave = t >> 6, lane = t & 63;
    const int quad = lane >> 4, l15 = lane & 15;
    const int m0 = blockIdx.x * 64;
    const int bq = m0 >> 14;                   // batch (tile never straddles)
    const int n0 = m0 & 16383;
    const int wm = (wave & 1) * 32, wn = (wave >> 1) * 128;
    const int lrow = lane >> 3, ls = lane & 7;
    const u16* OWb = OW + (size_t)bq * 131072;
    f4 acc[2][8];
#pragma unroll
    for (int i = 0; i < 2; ++i)
#pragma unroll
        for (int j = 0; j < 8; ++j) acc[i][j] = (f4){0.f, 0.f, 0.f, 0.f};

    for (int kc = 0; kc < 512; kc += 64) {
        if (kc) __syncthreads();
        const int h = kc >> 6;
        const u16* Ah = SW + ((size_t)(bq * 8 + h) * NB + n0) * 64;
#pragma unroll
        for (int q = 0; q < 10; ++q) {
            int gr = wave * 80 + q * 8;
            if (gr < 64) {
                int row = gr + lrow;
                int chunk = ls ^ lrow;
                gload_lds16(Ah + (size_t)row * 64 + chunk * 8, As + gr * 64);
            } else {
                int brow = gr - 64 + lrow;
                int chunk = ls ^ lrow;
                gload_lds16(OWb + (size_t)brow * 512 + kc + chunk * 8,
                            Bs + (gr - 64) * 64);
            }
        }
        __syncthreads();
#pragma unroll
        for (int kk = 0; kk < 2; ++kk) {
            short8 a[2], b[8];
#pragma unroll
            for (int i = 0; i < 2; ++i) {
                int R = wm + i * 16 + l15;
                a[i] = *(const short8*)(As + R * 64 + (((quad + kk * 4) ^ (R & 7)) << 3));
            }
#pragma unroll
            for (int j = 0; j < 8; ++j) {
                int Rb = wn + j * 16 + l15;
                b[j] = *(const short8*)(Bs + Rb * 64 + (((quad + kk * 4) ^ (Rb & 7)) << 3));
            }
#pragma unroll
            for (int i = 0; i < 2; ++i)
#pragma unroll
                for (int j = 0; j < 8; ++j)
                    acc[i][j] = __builtin_amdgcn_mfma_f32_16x16x32_bf16(
                        a[i], b[j], acc[i][j], 0, 0, 0);
        }
    }
    int colj[8];
    float bj[8];
#pragma unroll
    for (int j = 0; j < 8; ++j) { colj[j] = wn + j * 16 + l15; bj[j] = bias[colj[j]]; }
    const int half = wn >> 7;
#pragma unroll
    for (int i = 0; i < 2; ++i) {
#pragma unroll
        for (int r = 0; r < 4; ++r) {
            int row = wm + i * 16 + quad * 4 + r;
            size_t gbase = (size_t)(m0 + row) * 256;
            float s = 0.f, q2 = 0.f;
#pragma unroll
            for (int j = 0; j < 8; ++j) {
                float v = acc[i][j][r] + bj[j] + bfu(Hb[gbase + colj[j]]);
                Hb[gbase + colj[j]] = f2bf(v);
                acc[i][j][r] = v;
                s += v; q2 += v * v;
            }
#pragma unroll
            for (int o = 1; o < 16; o <<= 1) { s += __shfl_xor(s, o); q2 += __shfl_xor(q2, o); }
            if (l15 == 0) { rs2[half][row] = s; rq2[half][row] = q2; }
        }
    }
    __syncthreads();
    float gj[8], betj[8];
#pragma unroll
    for (int j = 0; j < 8; ++j) { gj[j] = lng[colj[j]]; betj[j] = lnb[colj[j]]; }
#pragma unroll
    for (int i = 0; i < 2; ++i) {
#pragma unroll
        for (int r = 0; r < 4; ++r) {
            int row = wm + i * 16 + quad * 4 + r;
            size_t gbase = (size_t)(m0 + row) * 256;
            float mean = (rs2[0][row] + rs2[1][row]) * (1.0f / 256.0f);
            float var = (rq2[0][row] + rq2[1][row]) * (1.0f / 256.0f) - mean * mean;
            float rstd = rsqrtf(var + 1e-5f);
#pragma unroll
            for (int j = 0; j < 8; ++j) {
                float y = (acc[i][j][r] - mean) * rstd * gj[j] + betj[j];
                Y[gbase + colj[j]] = f2bf(y);
            }
        }
    }
}

// ---------------- fused MLP: gelu(Y@W1+b1)@W2+b2 + residual + LN -----------
__global__ __launch_bounds__(256, 2) void gemm_mlp(
    const u16* __restrict__ A, const u16* __restrict__ W1,
    const float* __restrict__ b1, const u16* __restrict__ W2,
    const float* __restrict__ b2, const float* __restrict__ lng,
    const float* __restrict__ lnb, u16* __restrict__ Hb, u16* __restrict__ Y)
{
    __shared__ u16 As[64 * 64];
    __shared__ u16 Bs[256 * 64];
    __shared__ u16 hs[64 * 264];
    __shared__ float rs2[2][64], rq2[2][64];
    const int t = threadIdx.x;
    const int wave = t >> 6, lane = t & 63;
    const int quad = lane >> 4, l15 = lane & 15;
    const int m0 = blockIdx.x * 64;
    const int wm = (wave & 1) * 32, wn = (wave >> 1) * 128;
    const int lrow = lane >> 3, ls = lane & 7;
    f4 acc[2][8];
#pragma unroll
    for (int i = 0; i < 2; ++i)
#pragma unroll
        for (int j = 0; j < 8; ++j) acc[i][j] = (f4){0.f, 0.f, 0.f, 0.f};

    for (int kc = 0; kc < 256; kc += 64) {
        if (kc) __syncthreads();
#pragma unroll
        for (int q = 0; q < 10; ++q) {
            int gr = wave * 80 + q * 8;
            if (gr < 64) {
                int row = gr + lrow;
                gload_lds16(A + (size_t)(m0 + row) * 256 + kc + (ls ^ lrow) * 8,
                            As + gr * 64);
            } else {
                int brow = gr - 64 + lrow;
                gload_lds16(W1 + (size_t)brow * 256 + kc + (ls ^ lrow) * 8,
                            Bs + (gr - 64) * 64);
            }
        }
        __syncthreads();
#pragma unroll
        for (int kk = 0; kk < 2; ++kk) {
            short8 a[2], b[8];
#pragma unroll
            for (int i = 0; i < 2; ++i) {
                int R = wm + i * 16 + l15;
                a[i] = *(const short8*)(As + R * 64 + (((quad + kk * 4) ^ (R & 7)) << 3));
            }
#pragma unroll
            for (int j = 0; j < 8; ++j) {
                int Rb = wn + j * 16 + l15;
                b[j] = *(const short8*)(Bs + Rb * 64 + (((quad + kk * 4) ^ (Rb & 7)) << 3));
            }
#pragma unroll
            for (int i = 0; i < 2; ++i)
#pragma unroll
                for (int j = 0; j < 8; ++j)
                    acc[i][j] = __builtin_amdgcn_mfma_f32_16x16x32_bf16(
                        a[i], b[j], acc[i][j], 0, 0, 0);
        }
    }
    int colj[8];
#pragma unroll
    for (int j = 0; j < 8; ++j) colj[j] = wn + j * 16 + l15;
    {
        float bj[8];
#pragma unroll
        for (int j = 0; j < 8; ++j) bj[j] = b1[colj[j]];
#pragma unroll
        for (int i = 0; i < 2; ++i)
#pragma unroll
            for (int r = 0; r < 4; ++r) {
                int row = wm + i * 16 + quad * 4 + r;
#pragma unroll
                for (int j = 0; j < 8; ++j)
                    hs[row * 264 + colj[j]] = f2bf(gelu_f(acc[i][j][r] + bj[j]));
            }
    }
#pragma unroll
    for (int i = 0; i < 2; ++i)
#pragma unroll
        for (int j = 0; j < 8; ++j) acc[i][j] = (f4){0.f, 0.f, 0.f, 0.f};

    for (int kc = 0; kc < 256; kc += 64) {
        __syncthreads();
#pragma unroll
        for (int q = 0; q < 8; ++q) {
            int gr = wave * 64 + q * 8;
            int brow = gr + lrow;
            gload_lds16(W2 + (size_t)brow * 256 + kc + (ls ^ lrow) * 8,
                        Bs + gr * 64);
        }
        __syncthreads();
#pragma unroll
        for (int kk = 0; kk < 2; ++kk) {
            short8 a[2], b[8];
#pragma unroll
            for (int i = 0; i < 2; ++i) {
                int R = wm + i * 16 + l15;
                a[i] = *(const short8*)(hs + R * 264 + kc + kk * 32 + quad * 8);
            }
#pragma unroll
            for (int j = 0; j < 8; ++j) {
                int Rb = wn + j * 16 + l15;
                b[j] = *(const short8*)(Bs + Rb * 64 + (((quad + kk * 4) ^ (Rb & 7)) << 3));
            }
#pragma unroll
            for (int i = 0; i < 2; ++i)
#pragma unroll
                for (int j = 0; j < 8; ++j)
                    acc[i][j] = __builtin_amdgcn_mfma_f32_16x16x32_bf16(
                        a[i], b[j], acc[i][j], 0, 0, 0);
        }
    }
    float bj[8];
#pragma unroll
    for (int j = 0; j < 8; ++j) bj[j] = b2[colj[j]];
    const int half = wn >> 7;
#pragma unroll
    for (int i = 0; i < 2; ++i) {
#pragma unroll
        for (int r = 0; r < 4; ++r) {
            int row = wm + i * 16 + quad * 4 + r;
            size_t gbase = (size_t)(m0 + row) * 256;
            float s = 0.f, q2 = 0.f;
#pragma unroll
            for (int j = 0; j < 8; ++j) {
                float v = acc[i][j][r] + bj[j] + bfu(Hb[gbase + colj[j]]);
                Hb[gbase + colj[j]] = f2bf(v);
                acc[i][j][r] = v;
                s += v; q2 += v * v;
            }
#pragma unroll
            for (int o = 1; o < 16; o <<= 1) { s += __shfl_xor(s, o); q2 += __shfl_xor(q2, o); }
            if (l15 == 0) { rs2[half][row] = s; rq2[half][row] = q2; }
        }
    }
    __syncthreads();
    float gj[8], betj[8];
#pragma unroll
    for (int j = 0; j < 8; ++j) { gj[j] = lng[colj[j]]; betj[j] = lnb[colj[j]]; }
#pragma unroll
    for (int i = 0; i < 2; ++i) {
#pragma unroll
        for (int r = 0; r < 4; ++r) {
            int row = wm + i * 16 + quad * 4 + r;
            size_t gbase = (size_t)(m0 + row) * 256;
            float mean = (rs2[0][row] + rs2[1][row]) * (1.0f / 256.0f);
            float var = (rq2[0][row] + rq2[1][row]) * (1.0f / 256.0f) - mean * mean;
            float rstd = rsqrtf(var + 1e-5f);
#pragma unroll
            for (int j = 0; j < 8; ++j) {
                float y = (acc[i][j][r] - mean) * rstd * gj[j] + betj[j];
                Y[gbase + colj[j]] = f2bf(y);
            }
        }
    }
}

// ---------------- MFMA GEMM (gelu->bf16): 128x128, LDS-staged --------------
__global__ __launch_bounds__(256, 4) void gemm_gelu(
    const u16* __restrict__ A, const u16* __restrict__ Wt,
    const float* __restrict__ bias, u16* __restrict__ Cb)
{
    __shared__ u16 As[128 * 64];
    __shared__ u16 Bs[128 * 64];
    const int t = threadIdx.x;
    const int wave = t >> 6, lane = t & 63;
    const int quad = lane >> 4, l15 = lane & 15;
    const int m0 = blockIdx.x * 128;
    const int n0 = blockIdx.y * 128;
    const int wm = (wave & 1) * 64, wn = (wave >> 1) * 64;
    const int r0 = wave * 32;
    const int lrow = lane >> 3, ls = lane & 7;
    f4 acc[4][4];
#pragma unroll
    for (int i = 0; i < 4; ++i)
#pragma unroll
        for (int j = 0; j < 4; ++j) acc[i][j] = (f4){0.f, 0.f, 0.f, 0.f};

    for (int kc = 0; kc < 256; kc += 64) {
        if (kc) __syncthreads();
#pragma unroll
        for (int q = 0; q < 4; ++q) {
            int row = r0 + q * 8 + lrow;
            int chunk = ls ^ (row & 7);
            gload_lds16(A  + (size_t)(m0 + row) * 256 + kc + chunk * 8,
                        As + (r0 + q * 8) * 64);
            gload_lds16(Wt + (size_t)(n0 + row) * 256 + kc + chunk * 8,
                        Bs + (r0 + q * 8) * 64);
        }
        __syncthreads();
#pragma unroll
        for (int kk = 0; kk < 2; ++kk) {
            short8 a[4], b[4];
#pragma unroll
            for (int i = 0; i < 4; ++i) {
                int R = wm + i * 16 + l15;
                a[i] = *(const short8*)(As + R * 64 + (((quad + kk * 4) ^ (R & 7)) << 3));
            }
#pragma unroll
            for (int j = 0; j < 4; ++j) {
                int R = wn + j * 16 + l15;
                b[j] = *(const short8*)(Bs + R * 64 + (((quad + kk * 4) ^ (R & 7)) << 3));
            }
#pragma unroll
            for (int i = 0; i < 4; ++i)
#pragma unroll
                for (int j = 0; j < 4; ++j)
                    acc[i][j] = __builtin_amdgcn_mfma_f32_16x16x32_bf16(
                        a[i], b[j], acc[i][j], 0, 0, 0);
        }
    }
#pragma unroll
    for (int j = 0; j < 4; ++j) {
        int cj = n0 + wn + j * 16 + l15;
        float bj = bias[cj];
#pragma unroll
        for (int i = 0; i < 4; ++i) {
            int rbase = m0 + wm + i * 16 + quad * 4;
#pragma unroll
            for (int r = 0; r < 4; ++r) {
                float v = gelu_f(acc[i][j][r] + bj);
                Cb[(size_t)(rbase + r) * 256 + cj] = f2bf(v);
            }
        }
    }
}

// ---------------- merged slice+pfx GEMM: grid (256,6), LDS-staged ----------
__global__ __launch_bounds__(256, 4) void gemm_spfx(
    const u16* __restrict__ A, const u16* __restrict__ Wt,
    const float* __restrict__ bsp, const float* __restrict__ tempv,
    u16* __restrict__ SW, u16* __restrict__ FM)
{
    __shared__ u16 As[128 * 64];
    __shared__ u16 Bs[128 * 64];
    const int t = threadIdx.x;
    const int wave = t >> 6, lane = t & 63;
    const int quad = lane >> 4, l15 = lane & 15;
    const int m0 = blockIdx.x * 128;
    const int n0 = blockIdx.y * 128;
    const int wm = (wave & 1) * 64, wn = (wave >> 1) * 64;
    const int r0 = wave * 32;
    const int lrow = lane >> 3, ls = lane & 7;
    f4 acc[4][4];
#pragma unroll
    for (int i = 0; i < 4; ++i)
#pragma unroll
        for (int j = 0; j < 4; ++j) acc[i][j] = (f4){0.f, 0.f, 0.f, 0.f};

    for (int kc = 0; kc < 256; kc += 64) {
        if (kc) __syncthreads();
#pragma unroll
        for (int q = 0; q < 4; ++q) {
            int row = r0 + q * 8 + lrow;
            int chunk = ls ^ (row & 7);
            gload_lds16(A  + (size_t)(m0 + row) * 256 + kc + chunk * 8,
                        As + (r0 + q * 8) * 64);
            gload_lds16(Wt + (size_t)(n0 + row) * 256 + kc + chunk * 8,
                        Bs + (r0 + q * 8) * 64);
        }
        __syncthreads();
#pragma unroll
        for (int kk = 0; kk < 2; ++kk) {
            short8 a[4], b[4];
#pragma unroll
            for (int i = 0; i < 4; ++i) {
                int R = wm + i * 16 + l15;
                a[i] = *(const short8*)(As + R * 64 + (((quad + kk * 4) ^ (R & 7)) << 3));
            }
#pragma unroll
            for (int j = 0; j < 4; ++j) {
                int R = wn + j * 16 + l15;
                b[j] = *(const short8*)(Bs + R * 64 + (((quad + kk * 4) ^ (R & 7)) << 3));
            }
#pragma unroll
            for (int i = 0; i < 4; ++i)
#pragma unroll
                for (int j = 0; j < 4; ++j)
                    acc[i][j] = __builtin_amdgcn_mfma_f32_16x16x32_bf16(
                        a[i], b[j], acc[i][j], 0, 0, 0);
        }
    }
    float bj[4];
#pragma unroll
    for (int j = 0; j < 4; ++j) bj[j] = bsp[n0 + wn + j * 16 + l15];
    if (blockIdx.y < 4) {
        const int h = (n0 + wn) >> 6;
        const float itemp = 1.0f / tempv[h];
#pragma unroll
        for (int i = 0; i < 4; ++i) {
#pragma unroll
            for (int r = 0; r < 4; ++r) {
                float v[4];
                float mx = -3.0e38f;
#pragma unroll
                for (int j = 0; j < 4; ++j) {
                    v[j] = (acc[i][j][r] + bj[j]) * itemp;
                    mx = fmaxf(mx, v[j]);
                }
#pragma unroll
                for (int o = 1; o < 16; o <<= 1) mx = fmaxf(mx, __shfl_xor(mx, o));
                float s = 0.f;
#pragma unroll
                for (int j = 0; j < 4; ++j) { v[j] = expf(v[j] - mx); s += v[j]; }
#pragma unroll
                for (int o = 1; o < 16; o <<= 1) s += __shfl_xor(s, o);
                float inv = 1.0f / s;
                int m = m0 + wm + i * 16 + quad * 4 + r;
                int b = m >> 14, n = m & 16383;
                size_t base = (((size_t)(b * 8 + h)) * NB + n) * 64;
#pragma unroll
                for (int j = 0; j < 4; ++j)
                    SW[base + j * 16 + l15] = f2bf(v[j] * inv);
            }
        }
    } else {
        int cj = (n0 - 512) + wn + l15;
#pragma unroll
        for (int j = 0; j < 4; ++j) {
            int col = cj + j * 16;
#pragma unroll
            for (int i = 0; i < 4; ++i) {
                int rbase = m0 + wm + i * 16 + quad * 4;
#pragma unroll
                for (int r = 0; r < 4; ++r)
                    FM[(size_t)(rbase + r) * 256 + col] = f2bf(acc[i][j][r] + bj[j]);
            }
        }
    }
}

// ---------------- tok stage 1: per-chunk partials (64 chunks) --------------
__global__ __launch_bounds__(256) void tok1_kernel(
    const u16* __restrict__ FM, const u16* __restrict__ SW,
    float* __restrict__ TOKP, float* __restrict__ NORMP)
{
    int bh = blockIdx.x >> 6, chunk = blockIdx.x & 63;
    int b = bh >> 3, hd = bh & 7;
    int t = threadIdx.x, wave = t >> 6, lane = t & 63;
    int g0 = (lane >> 3) * 8, d0 = (lane & 7) * 4;
    float4 acc[8];
#pragma unroll
    for (int gi = 0; gi < 8; ++gi) acc[gi] = make_float4(0.f, 0.f, 0.f, 0.f);
    float4 n0a = make_float4(0.f, 0.f, 0.f, 0.f);
    float4 n1a = make_float4(0.f, 0.f, 0.f, 0.f);
    int nbase = chunk * 256 + wave * 64;
    const u16* fmB = FM + ((size_t)b * NB + nbase) * 256 + hd * 32 + d0;
    const u16* swB = SW + ((size_t)bh * NB + nbase) * 64 + g0;
    for (int j = 0; j < 64; ++j) {
        float4 f4v = dec4(*(const ushort4*)(fmB + (size_t)j * 256));
        float4 s0 = dec4(*(const ushort4*)(swB + (size_t)j * 64));
        float4 s1 = dec4(*(const ushort4*)(swB + (size_t)j * 64 + 4));
#define TOKACC(gi, sv)                                            \
        acc[gi].x = fmaf(f4v.x, sv, acc[gi].x);                   \
        acc[gi].y = fmaf(f4v.y, sv, acc[gi].y);                   \
        acc[gi].z = fmaf(f4v.z, sv, acc[gi].z);                   \
        acc[gi].w = fmaf(f4v.w, sv, acc[gi].w);
        TOKACC(0, s0.x) TOKACC(1, s0.y) TOKACC(2, s0.z) TOKACC(3, s0.w)
        TOKACC(4, s1.x) TOKACC(5, s1.y) TOKACC(6, s1.z) TOKACC(7, s1.w)
#undef TOKACC
        n0a.x += s0.x; n0a.y += s0.y; n0a.z += s0.z; n0a.w += s0.w;
        n1a.x += s1.x; n1a.y += s1.y; n1a.z += s1.z; n1a.w += s1.w;
    }
    __shared__ float red[4][2048];
    __shared__ float nred[4][64];
#pragma unroll
    for (int gi = 0; gi < 8; ++gi)
        *(float4*)&red[wave][(g0 + gi) * 32 + d0] = acc[gi];
    if ((lane & 7) == 0) {
        nred[wave][g0 + 0] = n0a.x; nred[wave][g0 + 1] = n0a.y;
        nred[wave][g0 + 2] = n0a.z; nred[wave][g0 + 3] = n0a.w;
        nred[wave][g0 + 4] = n1a.x; nred[wave][g0 + 5] = n1a.y;
        nred[wave][g0 + 6] = n1a.z; nred[wave][g0 + 7] = n1a.w;
    }
    __syncthreads();
    size_t tokBase = (size_t)(chunk * 16 + bh) * 2048;
#pragma unroll
    for (int k = 0; k < 8; ++k) {
        int c = t + 256 * k;
        TOKP[tokBase + c] = red[0][c] + red[1][c] + red[2][c] + red[3][c];
    }
    if (t < 64)
        NORMP[(chunk * 16 + bh) * 64 + t] = nred[0][t] + nred[1][t] + nred[2][t] + nred[3][t];
}

// ---------------- tok stage 2: parallel reduce over 64 chunks --------------
__global__ __launch_bounds__(256) void tok2_kernel(
    const float* __restrict__ TOKP, const float* __restrict__ NORMP,
    float* __restrict__ TOK, float* __restrict__ NORM)
{
    int idx = blockIdx.x * 256 + threadIdx.x;
    if (idx < 32768) {
        int bh = idx >> 11, c = idx & 2047;
        float s = 0.f;
#pragma unroll 8
        for (int ch = 0; ch < 64; ++ch) s += TOKP[(size_t)(ch * 16 + bh) * 2048 + c];
        TOK[idx] = s;
    } else if (idx < 33792) {
        int o = idx - 32768;
        int bh = o >> 6, g = o & 63;
        float s = 0.f;
#pragma unroll 8
        for (int ch = 0; ch < 64; ++ch) s += NORMP[(ch * 16 + bh) * 64 + g];
        NORM[o] = s;
    }
}

// ---------------- attention + OW = os @ out_w^T (per (b,h)) ----------------
__global__ __launch_bounds__(256) void attn_kernel(
    const float* __restrict__ TOK, const float* __restrict__ NORM,
    const float* __restrict__ qw, const float* __restrict__ kw,
    const float* __restrict__ vw, const u16* __restrict__ OWT,
    u16* __restrict__ OW)
{
    __shared__ float tokd[2048], qs[2048], ks[2048], vs[2048];
    __shared__ u16 osb[64 * 32];
    int bh = blockIdx.x;
    int b = bh >> 3, h = bh & 7;
    int t = threadIdx.x;
#pragma unroll
    for (int i = 0; i < 2; ++i) {
        int f4v = t + 256 * i;
        float4 v = *(const float4*)(TOK + (size_t)bh * 2048 + f4v * 4);
        float inv = 1.0f / (NORM[bh * 64 + (f4v >> 3)] + 1e-5f);
        v.x *= inv; v.y *= inv; v.z *= inv; v.w *= inv;
        *(float4*)&tokd[f4v * 4] = v;
    }
    __syncthreads();
#pragma unroll
    for (int i = 0; i < 8; ++i) {
        int f = t + 256 * i;
        int g = f >> 5, d = f & 31;
        const float* tr = tokd + g * 32;
        float aq = 0.f, ak = 0.f, av = 0.f;
#pragma unroll
        for (int e = 0; e < 32; ++e) {
            float tv = tr[e];
            aq = fmaf(tv, qw[e * 32 + d], aq);
            ak = fmaf(tv, kw[e * 32 + d], ak);
            av = fmaf(tv, vw[e * 32 + d], av);
        }
        qs[f] = aq; ks[f] = ak; vs[f] = av;
    }
    __syncthreads();
    int g = t >> 2, sub = t & 3;
    float4 qv[8];
#pragma unroll
    for (int e4 = 0; e4 < 8; ++e4) qv[e4] = *(const float4*)(qs + g * 32 + e4 * 4);
    float p[16];
    float mx = -3.0e38f;
#pragma unroll
    for (int mm = 0; mm < 16; ++mm) {
        int mI = sub * 16 + mm;
        const float4* kr = (const float4*)(ks + mI * 32);
        float s = 0.f;
#pragma unroll
        for (int e4 = 0; e4 < 8; ++e4) {
            float4 kv = kr[e4];
            s = fmaf(qv[e4].x, kv.x, s); s = fmaf(qv[e4].y, kv.y, s);
            s = fmaf(qv[e4].z, kv.z, s); s = fmaf(qv[e4].w, kv.w, s);
        }
        s *= 0.17677669529663687f;   // 1/sqrt(32)
        p[mm] = s;
        mx = fmaxf(mx, s);
    }
    mx = fmaxf(mx, __shfl_xor(mx, 1));
    mx = fmaxf(mx, __shfl_xor(mx, 2));
    float lsum = 0.f;
#pragma unroll
    for (int mm = 0; mm < 16; ++mm) { p[mm] = expf(p[mm] - mx); lsum += p[mm]; }
    lsum += __shfl_xor(lsum, 1);
    lsum += __shfl_xor(lsum, 2);
    float inv = 1.0f / lsum;
    float4 oa[8];
#pragma unroll
    for (int d4 = 0; d4 < 8; ++d4) oa[d4] = make_float4(0.f, 0.f, 0.f, 0.f);
#pragma unroll
    for (int mm = 0; mm < 16; ++mm) {
        int mI = sub * 16 + mm;
        const float4* vr = (const float4*)(vs + mI * 32);
        float pm = p[mm];
#pragma unroll
        for (int d4 = 0; d4 < 8; ++d4) {
            float4 vv = vr[d4];
            oa[d4].x = fmaf(pm, vv.x, oa[d4].x);
            oa[d4].y = fmaf(pm, vv.y, oa[d4].y);
            oa[d4].z = fmaf(pm, vv.z, oa[d4].z);
            oa[d4].w = fmaf(pm, vv.w, oa[d4].w);
        }
    }
#pragma unroll
    for (int d4 = 0; d4 < 8; ++d4) {
        oa[d4].x += __shfl_xor(oa[d4].x, 1); oa[d4].x += __shfl_xor(oa[d4].x, 2);
        oa[d4].y += __shfl_xor(oa[d4].y, 1); oa[d4].y += __shfl_xor(oa[d4].y, 2);
        oa[d4].z += __shfl_xor(oa[d4].z, 1); oa[d4].z += __shfl_xor(oa[d4].z, 2);
        oa[d4].w += __shfl_xor(oa[d4].w, 1); oa[d4].w += __shfl_xor(oa[d4].w, 2);
    }
    float4 r0 = oa[sub * 2], r1 = oa[sub * 2 + 1];
    osb[g * 32 + sub * 8 + 0] = f2bf(r0.x * inv);
    osb[g * 32 + sub * 8 + 1] = f2bf(r0.y * inv);
    osb[g * 32 + sub * 8 + 2] = f2bf(r0.z * inv);
    osb[g * 32 + sub * 8 + 3] = f2bf(r0.w * inv);
    osb[g * 32 + sub * 8 + 4] = f2bf(r1.x * inv);
    osb[g * 32 + sub * 8 + 5] = f2bf(r1.y * inv);
    osb[g * 32 + sub * 8 + 6] = f2bf(r1.z * inv);
    osb[g * 32 + sub * 8 + 7] = f2bf(r1.w * inv);
    __syncthreads();
    // OW[b][c][h*64+g] = sum_d os[g][d] * OWT[c][h*32+d]  via K=32 MFMA
    const int wave = t >> 6, lane = t & 63;
    const int quad = lane >> 4, l15 = lane & 15;
    const int c0 = wave * 64;
    short8 a[4], bb[4];
#pragma unroll
    for (int i = 0; i < 4; ++i)
        a[i] = *(const short8*)(osb + (i * 16 + l15) * 32 + quad * 8);
#pragma unroll
    for (int j = 0; j < 4; ++j)
        bb[j] = *(const short8*)(OWT + (size_t)(c0 + j * 16 + l15) * 256 + h * 32 + quad * 8);
    f4 accd[4][4];
#pragma unroll
    for (int i = 0; i < 4; ++i)
#pragma unroll
        for (int j = 0; j < 4; ++j) {
            accd[i][j] = (f4){0.f, 0.f, 0.f, 0.f};
            accd[i][j] = __builtin_amdgcn_mfma_f32_16x16x32_bf16(
                a[i], bb[j], accd[i][j], 0, 0, 0);
        }
    u16* OWb = OW + (size_t)b * 131072 + h * 64;
#pragma unroll
    for (int i = 0; i < 4; ++i)
#pragma unroll
        for (int j = 0; j < 4; ++j) {
            int c = c0 + j * 16 + l15;
#pragma unroll
            for (int r = 0; r < 4; ++r) {
                int gg = i * 16 + quad * 4 + r;
                OWb[(size_t)c * 512 + gg] = f2bf(accd[i][j][r]);
            }
        }
}

// ---------------- head stage 2: out = hid @ head_w2 + b2 -------------------
__global__ __launch_bounds__(256) void head2_kernel(
    const u16* __restrict__ HID, const float* __restrict__ w2,
    const float* __restrict__ b2, const void* tmp, void* __restrict__ OUT)
{
    int isbf = (((const u16*)tmp)[0] != 0);
    int lane = threadIdx.x & 63;
    size_t m = (size_t)blockIdx.x * 4 + (threadIdx.x >> 6);
    const float4 hv = dec4(*(const ushort4*)(HID + m * 256 + lane * 4));
    float4 a = make_float4(0.f, 0.f, 0.f, 0.f);
    float hcomp[4] = {hv.x, hv.y, hv.z, hv.w};
#pragma unroll
    for (int i = 0; i < 4; ++i) {
        const float4 wv = *(const float4*)(w2 + (lane * 4 + i) * 4);
        float h = hcomp[i];
        a.x = fmaf(h, wv.x, a.x); a.y = fmaf(h, wv.y, a.y);
        a.z = fmaf(h, wv.z, a.z); a.w = fmaf(h, wv.w, a.w);
    }
#pragma unroll
    for (int o = 32; o; o >>= 1) {
        a.x += __shfl_xor(a.x, o); a.y += __shfl_xor(a.y, o);
        a.z += __shfl_xor(a.z, o); a.w += __shfl_xor(a.w, o);
    }
    if (lane == 0) {
        float o0 = a.x + b2[0], o1 = a.y + b2[1], o2 = a.z + b2[2], o3 = a.w + b2[3];
        if (isbf) {
            ushort4 r; r.x = f2bf(o0); r.y = f2bf(o1); r.z = f2bf(o2); r.w = f2bf(o3);
            *(ushort4*)((u16*)OUT + m * 4) = r;
        } else {
            *(float4*)((float*)OUT + m * 4) = make_float4(o0, o1, o2, o3);
        }
    }
}

// ---------------------------------------------------------------------------
extern "C" void kernel_launch(void* const* d_in, const int* in_sizes, int n_in,
                              void* d_out, int out_size, void* d_ws, size_t ws_size,
                              hipStream_t stream)
{
    const void* x = d_in[0];      const void* fx = d_in[1];
    const void* pre_w1 = d_in[2]; const void* pre_b1 = d_in[3];
    const void* pre_w2 = d_in[4]; const void* pre_b2 = d_in[5];
    const void* placeholder = d_in[6];
    const void* ln1_g = d_in[7];  const void* ln1_b = d_in[8];
    const void* px_w = d_in[9];   const void* px_b = d_in[10];
    const void* pfx_w = d_in[11]; const void* pfx_b = d_in[12];
    const void* slice_w = d_in[13]; const void* slice_b = d_in[14];
    const void* temp = d_in[15];
    const void* q_w = d_in[16];   const void* k_w = d_in[17]; const void* v_w = d_in[18];
    const void* out_w = d_in[19]; const void* out_b = d_in[20];
    const void* ln2_g = d_in[21]; const void* ln2_b = d_in[22];
    const void* mlp_w1 = d_in[23]; const void* mlp_b1 = d_in[24];
    const void* mlp_w2 = d_in[25]; const void* mlp_b2 = d_in[26];
    const void* ln3_g = d_in[27]; const void* ln3_b = d_in[28];
    const void* head_w1 = d_in[29]; const void* head_b1 = d_in[30];
    const void* head_w2 = d_in[31]; const void* head_b2 = d_in[32];

    float* ws = (float*)d_ws;
    u16*   Hb    = (u16*)(ws + F_H);   // bf16 residual stream
    float* TOKP  = ws + F_TOKP;
    float* NORMP = ws + F_NORMP;
    float* TOKf  = ws + F_TOK;
    float* NORMf = ws + F_NORM;
    float* BIAS  = ws + F_BIAS;
    float* P     = ws + F_PARAMS;
    u16*   U     = (u16*)(ws + F_BF);
    u16*   WT    = U + U_WT;
    u16*   Yb    = U + U_Y;
    u16*   XMb   = U + U_XM;   // HID prologue; OW [2][256][512] in layer loop
    u16*   FMb   = U + U_FM;
    u16*   SWb   = U + U_SW;
    u16*   HIDb  = U + U_XM;

    cvt_kernel<<<910, 256, 0, stream>>>(x, fx, pre_w1, pre_b1, ln1_g, ln1_b,
        ln2_g, ln2_b, ln3_g, ln3_b, slice_w, slice_b, temp, q_w, k_w, v_w,
        head_w2, head_b2, P);
    prep_main<<<390, 256, 0, stream>>>(pre_w2, head_w1, pfx_w, out_w, mlp_w1,
        mlp_w2, pre_b2, placeholder, pfx_b, out_b, mlp_b1, mlp_b2, head_b1,
        temp, WT, BIAS);
    prep_pxsl<<<160, 256, 0, stream>>>(px_w, px_b, slice_w, slice_b, temp, WT, BIAS);
    pre1_kernel<<<8192, 256, 0, stream>>>(P, HIDb);

    dim3 gpl(256, 2);
    dim3 gsp(256, 6);
    // pre-MLP stage 2 + fused LN1[0]
    gemm_ln<512, false><<<512, 256, 0, stream>>>(HIDb, WT + WT_PRE2,
        BIAS + B_PB2C, P + P_LN1G, P + P_LN1B, Hb, Yb);

    for (int i = 0; i < 5; ++i) {
        gemm_spfx<<<gsp, 256, 0, stream>>>(Yb, WT + WT_SPFX + (size_t)i * 196608,
            BIAS + B_SP + i * 768, P + P_TEMP + i * 8, SWb, FMb);
        tok1_kernel<<<1024, 256, 0, stream>>>(FMb, SWb, TOKP, NORMP);
        tok2_kernel<<<132, 256, 0, stream>>>(TOKP, NORMP, TOKf, NORMf);
        attn_kernel<<<16, 256, 0, stream>>>(TOKf, NORMf, P + P_QW + i * 1024,
            P + P_KW + i * 1024, P + P_VW + i * 1024,
            WT + WT_OUT + i * 65536, XMb);
        // deslice + out-proj + residual + fused LN2[i]
        gemm_desl_ln<<<512, 256, 0, stream>>>(SWb, XMb, BIAS + B_OUTB + i * 256,
            P + P_LN2G + i * 256, P + P_LN2B + i * 256, Hb, Yb);
        // fused MLP: mlp1+gelu+mlp2 + residual + fused LN1[i+1] / LN3
        const float* ng = (i < 4) ? (P + P_LN1G + (i + 1) * 256) : (P + P_LN3G);
        const float* nb = (i < 4) ? (P + P_LN1B + (i + 1) * 256) : (P + P_LN3B);
        gemm_mlp<<<512, 256, 0, stream>>>(Yb, WT + WT_MLP1 + i * 65536,
            BIAS + B_M1B + i * 256, WT + WT_MLP2 + i * 65536,
            BIAS + B_M2B + i * 256, ng, nb, Hb, Yb);
    }

    gemm_gelu<<<gpl, 256, 0, stream>>>(Yb, WT + WT_HEAD1, BIAS + B_HB1, XMb);
    head2_kernel<<<8192, 256, 0, stream>>>(XMb, P + P_HW2, P + P_HB2, temp, d_out);
}

// Round 15
// 1044.894 us; speedup vs baseline: 1.0894x; 1.0894x over previous
//
#include <hip/hip_runtime.h>

// ---------------------------------------------------------------------------
// Transolver forward, MI355X. Round 15: exact revert to R13 (verified best,
// 1050us). R14's deslice/out-proj fold regressed (uncoalesced OW stores at
// 16 blocks, 70us x5). R13 = LDS-staged MFMA GEMMs + LN fused into producers
// + fused MLP pair + merged slice+pfx GEMM + 2-stage tok + bf16 residual.
// ---------------------------------------------------------------------------

#define MTOK 32768   // B*N
#define NB   16384   // N

typedef unsigned short u16;
using short8 = __attribute__((ext_vector_type(8))) short;
using f4     = __attribute__((ext_vector_type(4))) float;

__device__ __forceinline__ float bfu(u16 u) {
    return __uint_as_float(((unsigned)u) << 16);
}
__device__ __forceinline__ u16 f2bf(float f) {
    unsigned u = __float_as_uint(f);
    u += 0x7FFFu + ((u >> 16) & 1u);   // round-to-nearest-even
    return (u16)(u >> 16);
}
__device__ __forceinline__ float ldf(const void* p, int i, int isbf) {
    return isbf ? bfu(((const u16*)p)[i]) : ((const float*)p)[i];
}
__device__ __forceinline__ float4 dec4(ushort4 u) {
    return make_float4(bfu(u.x), bfu(u.y), bfu(u.z), bfu(u.w));
}
__device__ __forceinline__ float gelu_f(float x) {
    return 0.5f * x * (1.0f + erff(x * 0.7071067811865475f));
}

typedef __attribute__((address_space(1))) const unsigned int* as1p;
typedef __attribute__((address_space(3))) unsigned int* as3p;
__device__ __forceinline__ void gload_lds16(const u16* g, u16* l) {
    __builtin_amdgcn_global_load_lds((as1p)g, (as3p)l, 16, 0, 0);
}

// ---------------- workspace layout -----------------------------------------
#define F_H      ((size_t)0)          // u16 H [32768,256] (in fp32 slot)
#define F_OS     ((size_t)8388608)    // [16,2048]
#define F_TOKP   ((size_t)8421376)    // [64ch,16bh,2048]
#define F_NORMP  ((size_t)10518528)   // [64ch,16bh,64]
#define F_TOK    ((size_t)10584064)   // [16,2048]
#define F_NORM   ((size_t)10616832)   // [16,64]
#define F_BIAS   ((size_t)10617856)
#define F_PARAMS ((size_t)10626048)   // fp32 small params (232836)
#define F_BF     ((size_t)10858884)   // u16 region base (byte off %16 == 0)
// bias-internal (floats, rel to F_BIAS)
#define B_PB2C 0        // 256
#define B_OUTB 256      // 1280
#define B_M1B  1536     // 1280
#define B_M2B  2816     // 1280
#define B_HB1  4096     // 256
#define B_SP   4352     // [5][768]: 0..511 folded slice bias, 512..767 pfx_b
#define B_END  8192
// u16 region offsets
#define U_WT     ((size_t)0)
#define WT_PRE2  0                   // [256][512]
#define WT_HEAD1 131072              // [256][256]
#define WT_SPFX  196608              // 5 x [768][256]: rows 0..511 pxsl, 512..767 pfx
#define WT_OUT   1179648             // 5 x [256][256]
#define WT_MLP1  1507328
#define WT_MLP2  1835008
#define WT_END   2162688
#define U_Y   ((size_t)2162688)      // [32768,256] bf16
#define U_XM  ((size_t)10551296)     // [32768,256]; +FM doubles as HID [32768,512]
#define U_FM  ((size_t)18939904)
#define U_SW  ((size_t)27328512)     // [16,16384,64]
// total ws: 10858884*4 + 44105728*2 = 131,646,992 B (~125.6 MB)

// params-internal offsets (floats, rel to F_PARAMS)
#define P_X    0
#define P_FX   65536
#define P_W1   196608
#define P_B1   199680
#define P_LN1G 200192
#define P_LN1B 201472
#define P_LN2G 202752
#define P_LN2B 204032
#define P_LN3G 205312
#define P_LN3B 205568
#define P_SLW  205824
#define P_SLB  216064
#define P_TEMP 216384
#define P_QW   216448
#define P_KW   221568
#define P_VW   226688
#define P_HW2  231808
#define P_HB2  232832
#define P_END  232836

// ---------------- cvt: small params -> fp32 params region ------------------
__global__ __launch_bounds__(256) void cvt_kernel(
    const void* x, const void* fx, const void* w1, const void* b1,
    const void* l1g, const void* l1b, const void* l2g, const void* l2b,
    const void* l3g, const void* l3b, const void* slw, const void* slb,
    const void* tmp, const void* qw, const void* kw, const void* vw,
    const void* hw2, const void* hb2, float* __restrict__ P)
{
    int isbf = (((const u16*)tmp)[0] != 0);
    int idx = blockIdx.x * 256 + threadIdx.x;
    const void* s; int o;
    if      (idx < 65536)  { s = x;   o = idx; }
    else if (idx < 196608) { s = fx;  o = idx - 65536; }
    else if (idx < 199680) { s = w1;  o = idx - 196608; }
    else if (idx < 200192) { s = b1;  o = idx - 199680; }
    else if (idx < 201472) { s = l1g; o = idx - 200192; }
    else if (idx < 202752) { s = l1b; o = idx - 201472; }
    else if (idx < 204032) { s = l2g; o = idx - 202752; }
    else if (idx < 205312) { s = l2b; o = idx - 204032; }
    else if (idx < 205568) { s = l3g; o = idx - 205312; }
    else if (idx < 205824) { s = l3b; o = idx - 205568; }
    else if (idx < 216064) { s = slw; o = idx - 205824; }
    else if (idx < 216384) { s = slb; o = idx - 216064; }
    else if (idx < 216424) { s = tmp; o = idx - 216384; }
    else if (idx < 216448) { return; }
    else if (idx < 221568) { s = qw;  o = idx - 216448; }
    else if (idx < 226688) { s = kw;  o = idx - 221568; }
    else if (idx < 231808) { s = vw;  o = idx - 226688; }
    else if (idx < 232832) { s = hw2; o = idx - 231808; }
    else if (idx < 232836) { s = hb2; o = idx - 232832; }
    else return;
    P[idx] = ldf(s, o, isbf);
}

// ---------------- prep_main: LDS-tiled transpose -> bf16 [N][K]; biases ----
__global__ __launch_bounds__(256) void prep_main(
    const void* pre_w2, const void* head_w1, const void* pfx_w,
    const void* out_w, const void* mlp_w1, const void* mlp_w2,
    const void* pre_b2, const void* placeholder, const void* pfx_b,
    const void* out_b, const void* mlp_b1, const void* mlp_b2,
    const void* head_b1, const void* tmp,
    u16* __restrict__ WT, float* __restrict__ BIAS)
{
    int isbf = (((const u16*)tmp)[0] != 0);
    int blk = blockIdx.x;
    int t = threadIdx.x;
    if (blk < 368) {
        __shared__ float tile[64][65];
        const void* src; size_t srcoff; size_t dbase; int dstride;
        int k0, n0;
        if (blk < 32) {                       // pre_w2 [512,256] -> [256][512]
            int tk = blk >> 2, tn = blk & 3;
            src = pre_w2; srcoff = 0;
            k0 = tk * 64; n0 = tn * 64;
            dbase = WT_PRE2; dstride = 512;
        } else {
            int m = (blk - 32) >> 4, tl = (blk - 32) & 15;
            int tk = tl >> 2, tn = tl & 3;
            k0 = tk * 64; n0 = tn * 64; dstride = 256;
            if (m == 0)       { src = head_w1; srcoff = 0;               dbase = WT_HEAD1; }
            else if (m <= 5)  { int i = m - 1;  src = pfx_w;  srcoff = (size_t)i * 65536;
                                dbase = WT_SPFX + (size_t)i * 196608 + (size_t)512 * 256; }
            else if (m <= 10) { int i = m - 6;  src = out_w;  srcoff = (size_t)i * 65536;
                                dbase = WT_OUT + (size_t)i * 65536; }
            else if (m <= 15) { int i = m - 11; src = mlp_w1; srcoff = (size_t)i * 65536;
                                dbase = WT_MLP1 + (size_t)i * 65536; }
            else              { int i = m - 16; src = mlp_w2; srcoff = (size_t)i * 65536;
                                dbase = WT_MLP2 + (size_t)i * 65536; }
        }
#pragma unroll
        for (int p = 0; p < 16; ++p) {
            int flat = t + 256 * p;
            int r = flat >> 6, c = flat & 63;
            tile[r][c] = ldf(src, srcoff + (size_t)(k0 + r) * 256 + n0 + c, isbf);
        }
        __syncthreads();
#pragma unroll
        for (int p = 0; p < 16; ++p) {
            int flat = t + 256 * p;
            int r = flat >> 6, c = flat & 63;
            WT[dbase + (size_t)(n0 + r) * dstride + k0 + c] = f2bf(tile[c][r]);
        }
    } else {
        int idx = (blk - 368) * 256 + t;      // 0..5631
        if (idx < 256) {
            BIAS[B_PB2C + idx] = ldf(pre_b2, idx, isbf) + ldf(placeholder, idx, isbf);
        } else if (idx < 1536) {
            int o = idx - 256;  BIAS[B_OUTB + o] = ldf(out_b, o, isbf);
        } else if (idx < 2816) {
            int o = idx - 1536; BIAS[B_M1B + o] = ldf(mlp_b1, o, isbf);
        } else if (idx < 4096) {
            int o = idx - 2816; BIAS[B_M2B + o] = ldf(mlp_b2, o, isbf);
        } else if (idx < 4352) {
            int o = idx - 4096; BIAS[B_HB1 + o] = ldf(head_b1, o, isbf);
        } else if (idx < 5632) {
            int o = idx - 4352;
            int i = o >> 8, c = o & 255;
            BIAS[B_SP + i * 768 + 512 + c] = ldf(pfx_b, o, isbf);
        }
    }
}

// ---------------- prep_pxsl: tiled fold px_w@slice_w -> spfx rows 0..511 ---
__global__ __launch_bounds__(256) void prep_pxsl(
    const void* px_w, const void* px_b, const void* slw, const void* slb,
    const void* tmp, u16* __restrict__ WT, float* __restrict__ BIAS)
{
    int isbf = (((const u16*)tmp)[0] != 0);
    __shared__ float pxs[64 * 33];
    __shared__ float sls[2048];
    int blk = blockIdx.x;
    int i = blk >> 5, h = (blk >> 2) & 7, kb = blk & 3;
    int t = threadIdx.x;
#pragma unroll
    for (int p = 0; p < 8; ++p) {
        int flat = t + 256 * p;
        sls[flat] = ldf(slw, i * 2048 + flat, isbf);
        int k = flat >> 5, d = flat & 31;
        pxs[k * 33 + d] = ldf(px_w, i * 65536 + (kb * 64 + k) * 256 + h * 32 + d, isbf);
    }
    __syncthreads();
    int k = t & 63, gb = t >> 6;
    float acc[16];
#pragma unroll
    for (int gi = 0; gi < 16; ++gi) acc[gi] = 0.f;
#pragma unroll
    for (int d = 0; d < 32; ++d) {
        float pv = pxs[k * 33 + d];
        const float* sp = sls + d * 64 + gb * 16;
#pragma unroll
        for (int gi = 0; gi < 16; ++gi) acc[gi] = fmaf(pv, sp[gi], acc[gi]);
    }
    u16* WTp = WT + WT_SPFX + (size_t)i * 196608;
#pragma unroll
    for (int gi = 0; gi < 16; ++gi) {
        int n = h * 64 + gb * 16 + gi;
        WTp[n * 256 + kb * 64 + k] = f2bf(acc[gi]);
    }
    if (kb == 0 && t < 64) {
        int g = t;
        float a = ldf(slb, i * 64 + g, isbf);
#pragma unroll
        for (int d = 0; d < 32; ++d)
            a = fmaf(ldf(px_b, i * 256 + h * 32 + d, isbf), sls[d * 64 + g], a);
        BIAS[B_SP + i * 768 + h * 64 + g] = a;
    }
}

// ---------------- pre1: gelu(in6 @ pre_w1 + b1) -> bf16, conflict-free -----
__global__ __launch_bounds__(256) void pre1_kernel(
    const float* __restrict__ P, u16* __restrict__ HID)
{
    __shared__ float w1s[3072];
    __shared__ float b1s[512];
    int t = threadIdx.x;
#pragma unroll
    for (int p = 0; p < 12; ++p) w1s[t + 256 * p] = P[P_W1 + t + 256 * p];
    b1s[t] = P[P_B1 + t];
    b1s[t + 256] = P[P_B1 + t + 256];
    __syncthreads();
    int m = blockIdx.x * 4 + (t >> 6);
    int lane = t & 63;
    float xa = P[P_X + m * 2],      xb = P[P_X + m * 2 + 1];
    float fa = P[P_FX + m * 4],     fb = P[P_FX + m * 4 + 1];
    float fc = P[P_FX + m * 4 + 2], fd = P[P_FX + m * 4 + 3];
    size_t base = (size_t)m * 512 + lane;
#pragma unroll
    for (int jj = 0; jj < 8; ++jj) {
        int j = lane + 64 * jj;   // bank = lane%32 -> 2-way (free)
        float a = b1s[j];
        a = fmaf(xa, w1s[j], a);
        a = fmaf(xb, w1s[512 + j], a);
        a = fmaf(fa, w1s[1024 + j], a);
        a = fmaf(fb, w1s[1536 + j], a);
        a = fmaf(fc, w1s[2048 + j], a);
        a = fmaf(fd, w1s[2560 + j], a);
        HID[base + 64 * jj] = f2bf(gelu_f(a));
    }
}

// ---------------- LN-fused producer GEMM: 64x256, LDS-staged ---------------
template <int KK, bool RES>
__global__ __launch_bounds__(256, 3) void gemm_ln(
    const u16* __restrict__ A, const u16* __restrict__ Wt,
    const float* __restrict__ bias, const float* __restrict__ lng,
    const float* __restrict__ lnb, u16* __restrict__ Hb, u16* __restrict__ Y)
{
    __shared__ u16 As[64 * 64];
    __shared__ u16 Bs[256 * 64];
    __shared__ float rs2[2][64], rq2[2][64];
    const int t = threadIdx.x;
    const int wave = t >> 6, lane = t & 63;
    const int quad = lane >> 4, l15 = lane & 15;
    const int m0 = blockIdx.x * 64;
    const int wm = (wave & 1) * 32, wn = (wave >> 1) * 128;
    const int lrow = lane >> 3, ls = lane & 7;
    f4 acc[2][8];
#pragma unroll
    for (int i = 0; i < 2; ++i)
#pragma unroll
        for (int j = 0; j < 8; ++j) acc[i][j] = (f4){0.f, 0.f, 0.f, 0.f};

    for (int kc = 0; kc < KK; kc += 64) {
        if (kc) __syncthreads();
#pragma unroll
        for (int q = 0; q < 10; ++q) {
            int gr = wave * 80 + q * 8;
            if (gr < 64) {
                int row = gr + lrow;
                int chunk = ls ^ lrow;
                gload_lds16(A + (size_t)(m0 + row) * KK + kc + chunk * 8,
                            As + gr * 64);
            } else {
                int brow = gr - 64 + lrow;
                int chunk = ls ^ lrow;
                gload_lds16(Wt + (size_t)brow * KK + kc + chunk * 8,
                            Bs + (gr - 64) * 64);
            }
        }
        __syncthreads();
#pragma unroll
        for (int kk = 0; kk < 2; ++kk) {
            short8 a[2], b[8];
#pragma unroll
            for (int i = 0; i < 2; ++i) {
                int R = wm + i * 16 + l15;
                a[i] = *(const short8*)(As + R * 64 + (((quad + kk * 4) ^ (R & 7)) << 3));
            }
#pragma unroll
            for (int j = 0; j < 8; ++j) {
                int Rb = wn + j * 16 + l15;
                b[j] = *(const short8*)(Bs + Rb * 64 + (((quad + kk * 4) ^ (Rb & 7)) << 3));
            }
#pragma unroll
            for (int i = 0; i < 2; ++i)
#pragma unroll
                for (int j = 0; j < 8; ++j)
                    acc[i][j] = __builtin_amdgcn_mfma_f32_16x16x32_bf16(
                        a[i], b[j], acc[i][j], 0, 0, 0);
        }
    }
    int colj[8];
    float bj[8];
#pragma unroll
    for (int j = 0; j < 8; ++j) { colj[j] = wn + j * 16 + l15; bj[j] = bias[colj[j]]; }
    const int half = wn >> 7;
#pragma unroll
    for (int i = 0; i < 2; ++i) {
#pragma unroll
        for (int r = 0; r < 4; ++r) {
            int row = wm + i * 16 + quad * 4 + r;
            size_t gbase = (size_t)(m0 + row) * 256;
            float s = 0.f, q2 = 0.f;
#pragma unroll
            for (int j = 0; j < 8; ++j) {
                float v = acc[i][j][r] + bj[j];
                if (RES) v += bfu(Hb[gbase + colj[j]]);
                Hb[gbase + colj[j]] = f2bf(v);
                acc[i][j][r] = v;
                s += v; q2 += v * v;
            }
#pragma unroll
            for (int o = 1; o < 16; o <<= 1) { s += __shfl_xor(s, o); q2 += __shfl_xor(q2, o); }
            if (l15 == 0) { rs2[half][row] = s; rq2[half][row] = q2; }
        }
    }
    __syncthreads();
    float gj[8], betj[8];
#pragma unroll
    for (int j = 0; j < 8; ++j) { gj[j] = lng[colj[j]]; betj[j] = lnb[colj[j]]; }
#pragma unroll
    for (int i = 0; i < 2; ++i) {
#pragma unroll
        for (int r = 0; r < 4; ++r) {
            int row = wm + i * 16 + quad * 4 + r;
            size_t gbase = (size_t)(m0 + row) * 256;
            float mean = (rs2[0][row] + rs2[1][row]) * (1.0f / 256.0f);
            float var = (rq2[0][row] + rq2[1][row]) * (1.0f / 256.0f) - mean * mean;
            float rstd = rsqrtf(var + 1e-5f);
#pragma unroll
            for (int j = 0; j < 8; ++j) {
                float y = (acc[i][j][r] - mean) * rstd * gj[j] + betj[j];
                Y[gbase + colj[j]] = f2bf(y);
            }
        }
    }
}

// ---------------- fused MLP: gelu(Y@W1+b1)@W2+b2 + residual + LN -----------
// 64x256 full-row tile; hidden kept in LDS hs[64][264] (bf16, padded).
__global__ __launch_bounds__(256, 2) void gemm_mlp(
    const u16* __restrict__ A, const u16* __restrict__ W1,
    const float* __restrict__ b1, const u16* __restrict__ W2,
    const float* __restrict__ b2, const float* __restrict__ lng,
    const float* __restrict__ lnb, u16* __restrict__ Hb, u16* __restrict__ Y)
{
    __shared__ u16 As[64 * 64];
    __shared__ u16 Bs[256 * 64];
    __shared__ u16 hs[64 * 264];
    __shared__ float rs2[2][64], rq2[2][64];
    const int t = threadIdx.x;
    const int wave = t >> 6, lane = t & 63;
    const int quad = lane >> 4, l15 = lane & 15;
    const int m0 = blockIdx.x * 64;
    const int wm = (wave & 1) * 32, wn = (wave >> 1) * 128;
    const int lrow = lane >> 3, ls = lane & 7;
    f4 acc[2][8];
#pragma unroll
    for (int i = 0; i < 2; ++i)
#pragma unroll
        for (int j = 0; j < 8; ++j) acc[i][j] = (f4){0.f, 0.f, 0.f, 0.f};

    // ---- stage 1: hid = gelu(A @ W1 + b1) ----
    for (int kc = 0; kc < 256; kc += 64) {
        if (kc) __syncthreads();
#pragma unroll
        for (int q = 0; q < 10; ++q) {
            int gr = wave * 80 + q * 8;
            if (gr < 64) {
                int row = gr + lrow;
                gload_lds16(A + (size_t)(m0 + row) * 256 + kc + (ls ^ lrow) * 8,
                            As + gr * 64);
            } else {
                int brow = gr - 64 + lrow;
                gload_lds16(W1 + (size_t)brow * 256 + kc + (ls ^ lrow) * 8,
                            Bs + (gr - 64) * 64);
            }
        }
        __syncthreads();
#pragma unroll
        for (int kk = 0; kk < 2; ++kk) {
            short8 a[2], b[8];
#pragma unroll
            for (int i = 0; i < 2; ++i) {
                int R = wm + i * 16 + l15;
                a[i] = *(const short8*)(As + R * 64 + (((quad + kk * 4) ^ (R & 7)) << 3));
            }
#pragma unroll
            for (int j = 0; j < 8; ++j) {
                int Rb = wn + j * 16 + l15;
                b[j] = *(const short8*)(Bs + Rb * 64 + (((quad + kk * 4) ^ (Rb & 7)) << 3));
            }
#pragma unroll
            for (int i = 0; i < 2; ++i)
#pragma unroll
                for (int j = 0; j < 8; ++j)
                    acc[i][j] = __builtin_amdgcn_mfma_f32_16x16x32_bf16(
                        a[i], b[j], acc[i][j], 0, 0, 0);
        }
    }
    int colj[8];
#pragma unroll
    for (int j = 0; j < 8; ++j) colj[j] = wn + j * 16 + l15;
    {
        float bj[8];
#pragma unroll
        for (int j = 0; j < 8; ++j) bj[j] = b1[colj[j]];
#pragma unroll
        for (int i = 0; i < 2; ++i)
#pragma unroll
            for (int r = 0; r < 4; ++r) {
                int row = wm + i * 16 + quad * 4 + r;
#pragma unroll
                for (int j = 0; j < 8; ++j)
                    hs[row * 264 + colj[j]] = f2bf(gelu_f(acc[i][j][r] + bj[j]));
            }
    }
#pragma unroll
    for (int i = 0; i < 2; ++i)
#pragma unroll
        for (int j = 0; j < 8; ++j) acc[i][j] = (f4){0.f, 0.f, 0.f, 0.f};

    // ---- stage 2: out = hid @ W2 + b2 (+H residual) -> LN ----
    for (int kc = 0; kc < 256; kc += 64) {
        __syncthreads();   // protects Bs reuse + hs writes (1st iter)
#pragma unroll
        for (int q = 0; q < 8; ++q) {
            int gr = wave * 64 + q * 8;
            int brow = gr + lrow;
            gload_lds16(W2 + (size_t)brow * 256 + kc + (ls ^ lrow) * 8,
                        Bs + gr * 64);
        }
        __syncthreads();
#pragma unroll
        for (int kk = 0; kk < 2; ++kk) {
            short8 a[2], b[8];
#pragma unroll
            for (int i = 0; i < 2; ++i) {
                int R = wm + i * 16 + l15;
                a[i] = *(const short8*)(hs + R * 264 + kc + kk * 32 + quad * 8);
            }
#pragma unroll
            for (int j = 0; j < 8; ++j) {
                int Rb = wn + j * 16 + l15;
                b[j] = *(const short8*)(Bs + Rb * 64 + (((quad + kk * 4) ^ (Rb & 7)) << 3));
            }
#pragma unroll
            for (int i = 0; i < 2; ++i)
#pragma unroll
                for (int j = 0; j < 8; ++j)
                    acc[i][j] = __builtin_amdgcn_mfma_f32_16x16x32_bf16(
                        a[i], b[j], acc[i][j], 0, 0, 0);
        }
    }
    float bj[8];
#pragma unroll
    for (int j = 0; j < 8; ++j) bj[j] = b2[colj[j]];
    const int half = wn >> 7;
#pragma unroll
    for (int i = 0; i < 2; ++i) {
#pragma unroll
        for (int r = 0; r < 4; ++r) {
            int row = wm + i * 16 + quad * 4 + r;
            size_t gbase = (size_t)(m0 + row) * 256;
            float s = 0.f, q2 = 0.f;
#pragma unroll
            for (int j = 0; j < 8; ++j) {
                float v = acc[i][j][r] + bj[j] + bfu(Hb[gbase + colj[j]]);
                Hb[gbase + colj[j]] = f2bf(v);
                acc[i][j][r] = v;
                s += v; q2 += v * v;
            }
#pragma unroll
            for (int o = 1; o < 16; o <<= 1) { s += __shfl_xor(s, o); q2 += __shfl_xor(q2, o); }
            if (l15 == 0) { rs2[half][row] = s; rq2[half][row] = q2; }
        }
    }
    __syncthreads();
    float gj[8], betj[8];
#pragma unroll
    for (int j = 0; j < 8; ++j) { gj[j] = lng[colj[j]]; betj[j] = lnb[colj[j]]; }
#pragma unroll
    for (int i = 0; i < 2; ++i) {
#pragma unroll
        for (int r = 0; r < 4; ++r) {
            int row = wm + i * 16 + quad * 4 + r;
            size_t gbase = (size_t)(m0 + row) * 256;
            float mean = (rs2[0][row] + rs2[1][row]) * (1.0f / 256.0f);
            float var = (rq2[0][row] + rq2[1][row]) * (1.0f / 256.0f) - mean * mean;
            float rstd = rsqrtf(var + 1e-5f);
#pragma unroll
            for (int j = 0; j < 8; ++j) {
                float y = (acc[i][j][r] - mean) * rstd * gj[j] + betj[j];
                Y[gbase + colj[j]] = f2bf(y);
            }
        }
    }
}

// ---------------- MFMA GEMM (gelu->bf16): 128x128, LDS-staged --------------
__global__ __launch_bounds__(256, 4) void gemm_gelu(
    const u16* __restrict__ A, const u16* __restrict__ Wt,
    const float* __restrict__ bias, u16* __restrict__ Cb)
{
    __shared__ u16 As[128 * 64];
    __shared__ u16 Bs[128 * 64];
    const int t = threadIdx.x;
    const int wave = t >> 6, lane = t & 63;
    const int quad = lane >> 4, l15 = lane & 15;
    const int m0 = blockIdx.x * 128;
    const int n0 = blockIdx.y * 128;
    const int wm = (wave & 1) * 64, wn = (wave >> 1) * 64;
    const int r0 = wave * 32;
    const int lrow = lane >> 3, ls = lane & 7;
    f4 acc[4][4];
#pragma unroll
    for (int i = 0; i < 4; ++i)
#pragma unroll
        for (int j = 0; j < 4; ++j) acc[i][j] = (f4){0.f, 0.f, 0.f, 0.f};

    for (int kc = 0; kc < 256; kc += 64) {
        if (kc) __syncthreads();
#pragma unroll
        for (int q = 0; q < 4; ++q) {
            int row = r0 + q * 8 + lrow;
            int chunk = ls ^ (row & 7);
            gload_lds16(A  + (size_t)(m0 + row) * 256 + kc + chunk * 8,
                        As + (r0 + q * 8) * 64);
            gload_lds16(Wt + (size_t)(n0 + row) * 256 + kc + chunk * 8,
                        Bs + (r0 + q * 8) * 64);
        }
        __syncthreads();
#pragma unroll
        for (int kk = 0; kk < 2; ++kk) {
            short8 a[4], b[4];
#pragma unroll
            for (int i = 0; i < 4; ++i) {
                int R = wm + i * 16 + l15;
                a[i] = *(const short8*)(As + R * 64 + (((quad + kk * 4) ^ (R & 7)) << 3));
            }
#pragma unroll
            for (int j = 0; j < 4; ++j) {
                int R = wn + j * 16 + l15;
                b[j] = *(const short8*)(Bs + R * 64 + (((quad + kk * 4) ^ (R & 7)) << 3));
            }
#pragma unroll
            for (int i = 0; i < 4; ++i)
#pragma unroll
                for (int j = 0; j < 4; ++j)
                    acc[i][j] = __builtin_amdgcn_mfma_f32_16x16x32_bf16(
                        a[i], b[j], acc[i][j], 0, 0, 0);
        }
    }
#pragma unroll
    for (int j = 0; j < 4; ++j) {
        int cj = n0 + wn + j * 16 + l15;
        float bj = bias[cj];
#pragma unroll
        for (int i = 0; i < 4; ++i) {
            int rbase = m0 + wm + i * 16 + quad * 4;
#pragma unroll
            for (int r = 0; r < 4; ++r) {
                float v = gelu_f(acc[i][j][r] + bj);
                Cb[(size_t)(rbase + r) * 256 + cj] = f2bf(v);
            }
        }
    }
}

// ---------------- merged slice+pfx GEMM: grid (256,6), LDS-staged ----------
__global__ __launch_bounds__(256, 4) void gemm_spfx(
    const u16* __restrict__ A, const u16* __restrict__ Wt,
    const float* __restrict__ bsp, const float* __restrict__ tempv,
    u16* __restrict__ SW, u16* __restrict__ FM)
{
    __shared__ u16 As[128 * 64];
    __shared__ u16 Bs[128 * 64];
    const int t = threadIdx.x;
    const int wave = t >> 6, lane = t & 63;
    const int quad = lane >> 4, l15 = lane & 15;
    const int m0 = blockIdx.x * 128;
    const int n0 = blockIdx.y * 128;
    const int wm = (wave & 1) * 64, wn = (wave >> 1) * 64;
    const int r0 = wave * 32;
    const int lrow = lane >> 3, ls = lane & 7;
    f4 acc[4][4];
#pragma unroll
    for (int i = 0; i < 4; ++i)
#pragma unroll
        for (int j = 0; j < 4; ++j) acc[i][j] = (f4){0.f, 0.f, 0.f, 0.f};

    for (int kc = 0; kc < 256; kc += 64) {
        if (kc) __syncthreads();
#pragma unroll
        for (int q = 0; q < 4; ++q) {
            int row = r0 + q * 8 + lrow;
            int chunk = ls ^ (row & 7);
            gload_lds16(A  + (size_t)(m0 + row) * 256 + kc + chunk * 8,
                        As + (r0 + q * 8) * 64);
            gload_lds16(Wt + (size_t)(n0 + row) * 256 + kc + chunk * 8,
                        Bs + (r0 + q * 8) * 64);
        }
        __syncthreads();
#pragma unroll
        for (int kk = 0; kk < 2; ++kk) {
            short8 a[4], b[4];
#pragma unroll
            for (int i = 0; i < 4; ++i) {
                int R = wm + i * 16 + l15;
                a[i] = *(const short8*)(As + R * 64 + (((quad + kk * 4) ^ (R & 7)) << 3));
            }
#pragma unroll
            for (int j = 0; j < 4; ++j) {
                int R = wn + j * 16 + l15;
                b[j] = *(const short8*)(Bs + R * 64 + (((quad + kk * 4) ^ (R & 7)) << 3));
            }
#pragma unroll
            for (int i = 0; i < 4; ++i)
#pragma unroll
                for (int j = 0; j < 4; ++j)
                    acc[i][j] = __builtin_amdgcn_mfma_f32_16x16x32_bf16(
                        a[i], b[j], acc[i][j], 0, 0, 0);
        }
    }
    float bj[4];
#pragma unroll
    for (int j = 0; j < 4; ++j) bj[j] = bsp[n0 + wn + j * 16 + l15];
    if (blockIdx.y < 4) {
        const int h = (n0 + wn) >> 6;
        const float itemp = 1.0f / tempv[h];
#pragma unroll
        for (int i = 0; i < 4; ++i) {
#pragma unroll
            for (int r = 0; r < 4; ++r) {
                float v[4];
                float mx = -3.0e38f;
#pragma unroll
                for (int j = 0; j < 4; ++j) {
                    v[j] = (acc[i][j][r] + bj[j]) * itemp;
                    mx = fmaxf(mx, v[j]);
                }
#pragma unroll
                for (int o = 1; o < 16; o <<= 1) mx = fmaxf(mx, __shfl_xor(mx, o));
                float s = 0.f;
#pragma unroll
                for (int j = 0; j < 4; ++j) { v[j] = expf(v[j] - mx); s += v[j]; }
#pragma unroll
                for (int o = 1; o < 16; o <<= 1) s += __shfl_xor(s, o);
                float inv = 1.0f / s;
                int m = m0 + wm + i * 16 + quad * 4 + r;
                int b = m >> 14, n = m & 16383;
                size_t base = (((size_t)(b * 8 + h)) * NB + n) * 64;
#pragma unroll
                for (int j = 0; j < 4; ++j)
                    SW[base + j * 16 + l15] = f2bf(v[j] * inv);
            }
        }
    } else {
        int cj = (n0 - 512) + wn + l15;
#pragma unroll
        for (int j = 0; j < 4; ++j) {
            int col = cj + j * 16;
#pragma unroll
            for (int i = 0; i < 4; ++i) {
                int rbase = m0 + wm + i * 16 + quad * 4;
#pragma unroll
                for (int r = 0; r < 4; ++r)
                    FM[(size_t)(rbase + r) * 256 + col] = f2bf(acc[i][j][r] + bj[j]);
            }
        }
    }
}

// ---------------- tok stage 1: per-chunk partials (64 chunks) --------------
__global__ __launch_bounds__(256) void tok1_kernel(
    const u16* __restrict__ FM, const u16* __restrict__ SW,
    float* __restrict__ TOKP, float* __restrict__ NORMP)
{
    int bh = blockIdx.x >> 6, chunk = blockIdx.x & 63;
    int b = bh >> 3, hd = bh & 7;
    int t = threadIdx.x, wave = t >> 6, lane = t & 63;
    int g0 = (lane >> 3) * 8, d0 = (lane & 7) * 4;
    float4 acc[8];
#pragma unroll
    for (int gi = 0; gi < 8; ++gi) acc[gi] = make_float4(0.f, 0.f, 0.f, 0.f);
    float4 n0a = make_float4(0.f, 0.f, 0.f, 0.f);
    float4 n1a = make_float4(0.f, 0.f, 0.f, 0.f);
    int nbase = chunk * 256 + wave * 64;
    const u16* fmB = FM + ((size_t)b * NB + nbase) * 256 + hd * 32 + d0;
    const u16* swB = SW + ((size_t)bh * NB + nbase) * 64 + g0;
    for (int j = 0; j < 64; ++j) {
        float4 f4v = dec4(*(const ushort4*)(fmB + (size_t)j * 256));
        float4 s0 = dec4(*(const ushort4*)(swB + (size_t)j * 64));
        float4 s1 = dec4(*(const ushort4*)(swB + (size_t)j * 64 + 4));
#define TOKACC(gi, sv)                                            \
        acc[gi].x = fmaf(f4v.x, sv, acc[gi].x);                   \
        acc[gi].y = fmaf(f4v.y, sv, acc[gi].y);                   \
        acc[gi].z = fmaf(f4v.z, sv, acc[gi].z);                   \
        acc[gi].w = fmaf(f4v.w, sv, acc[gi].w);
        TOKACC(0, s0.x) TOKACC(1, s0.y) TOKACC(2, s0.z) TOKACC(3, s0.w)
        TOKACC(4, s1.x) TOKACC(5, s1.y) TOKACC(6, s1.z) TOKACC(7, s1.w)
#undef TOKACC
        n0a.x += s0.x; n0a.y += s0.y; n0a.z += s0.z; n0a.w += s0.w;
        n1a.x += s1.x; n1a.y += s1.y; n1a.z += s1.z; n1a.w += s1.w;
    }
    __shared__ float red[4][2048];
    __shared__ float nred[4][64];
#pragma unroll
    for (int gi = 0; gi < 8; ++gi)
        *(float4*)&red[wave][(g0 + gi) * 32 + d0] = acc[gi];
    if ((lane & 7) == 0) {
        nred[wave][g0 + 0] = n0a.x; nred[wave][g0 + 1] = n0a.y;
        nred[wave][g0 + 2] = n0a.z; nred[wave][g0 + 3] = n0a.w;
        nred[wave][g0 + 4] = n1a.x; nred[wave][g0 + 5] = n1a.y;
        nred[wave][g0 + 6] = n1a.z; nred[wave][g0 + 7] = n1a.w;
    }
    __syncthreads();
    size_t tokBase = (size_t)(chunk * 16 + bh) * 2048;
#pragma unroll
    for (int k = 0; k < 8; ++k) {
        int c = t + 256 * k;
        TOKP[tokBase + c] = red[0][c] + red[1][c] + red[2][c] + red[3][c];
    }
    if (t < 64)
        NORMP[(chunk * 16 + bh) * 64 + t] = nred[0][t] + nred[1][t] + nred[2][t] + nred[3][t];
}

// ---------------- tok stage 2: parallel reduce over 64 chunks --------------
__global__ __launch_bounds__(256) void tok2_kernel(
    const float* __restrict__ TOKP, const float* __restrict__ NORMP,
    float* __restrict__ TOK, float* __restrict__ NORM)
{
    int idx = blockIdx.x * 256 + threadIdx.x;
    if (idx < 32768) {
        int bh = idx >> 11, c = idx & 2047;
        float s = 0.f;
#pragma unroll 8
        for (int ch = 0; ch < 64; ++ch) s += TOKP[(size_t)(ch * 16 + bh) * 2048 + c];
        TOK[idx] = s;
    } else if (idx < 33792) {
        int o = idx - 32768;
        int bh = o >> 6, g = o & 63;
        float s = 0.f;
#pragma unroll 8
        for (int ch = 0; ch < 64; ++ch) s += NORMP[(ch * 16 + bh) * 64 + g];
        NORM[o] = s;
    }
}

// ---------------- attention over G=64 tokens (block per (b,h)) -------------
__global__ __launch_bounds__(256) void attn_kernel(
    const float* __restrict__ TOK, const float* __restrict__ NORM,
    const float* __restrict__ qw, const float* __restrict__ kw,
    const float* __restrict__ vw, float* __restrict__ OS)
{
    __shared__ float tokd[2048], qs[2048], ks[2048], vs[2048];
    int bh = blockIdx.x;
    int t = threadIdx.x;
#pragma unroll
    for (int i = 0; i < 2; ++i) {
        int f4v = t + 256 * i;
        float4 v = *(const float4*)(TOK + (size_t)bh * 2048 + f4v * 4);
        float inv = 1.0f / (NORM[bh * 64 + (f4v >> 3)] + 1e-5f);
        v.x *= inv; v.y *= inv; v.z *= inv; v.w *= inv;
        *(float4*)&tokd[f4v * 4] = v;
    }
    __syncthreads();
#pragma unroll
    for (int i = 0; i < 8; ++i) {
        int f = t + 256 * i;
        int g = f >> 5, d = f & 31;
        const float* tr = tokd + g * 32;
        float aq = 0.f, ak = 0.f, av = 0.f;
#pragma unroll
        for (int e = 0; e < 32; ++e) {
            float tv = tr[e];
            aq = fmaf(tv, qw[e * 32 + d], aq);
            ak = fmaf(tv, kw[e * 32 + d], ak);
            av = fmaf(tv, vw[e * 32 + d], av);
        }
        qs[f] = aq; ks[f] = ak; vs[f] = av;
    }
    __syncthreads();
    int g = t >> 2, sub = t & 3;
    float4 qv[8];
#pragma unroll
    for (int e4 = 0; e4 < 8; ++e4) qv[e4] = *(const float4*)(qs + g * 32 + e4 * 4);
    float p[16];
    float mx = -3.0e38f;
#pragma unroll
    for (int mm = 0; mm < 16; ++mm) {
        int mI = sub * 16 + mm;
        const float4* kr = (const float4*)(ks + mI * 32);
        float s = 0.f;
#pragma unroll
        for (int e4 = 0; e4 < 8; ++e4) {
            float4 kv = kr[e4];
            s = fmaf(qv[e4].x, kv.x, s); s = fmaf(qv[e4].y, kv.y, s);
            s = fmaf(qv[e4].z, kv.z, s); s = fmaf(qv[e4].w, kv.w, s);
        }
        s *= 0.17677669529663687f;   // 1/sqrt(32)
        p[mm] = s;
        mx = fmaxf(mx, s);
    }
    mx = fmaxf(mx, __shfl_xor(mx, 1));
    mx = fmaxf(mx, __shfl_xor(mx, 2));
    float lsum = 0.f;
#pragma unroll
    for (int mm = 0; mm < 16; ++mm) { p[mm] = expf(p[mm] - mx); lsum += p[mm]; }
    lsum += __shfl_xor(lsum, 1);
    lsum += __shfl_xor(lsum, 2);
    float inv = 1.0f / lsum;
    float4 oa[8];
#pragma unroll
    for (int d4 = 0; d4 < 8; ++d4) oa[d4] = make_float4(0.f, 0.f, 0.f, 0.f);
#pragma unroll
    for (int mm = 0; mm < 16; ++mm) {
        int mI = sub * 16 + mm;
        const float4* vr = (const float4*)(vs + mI * 32);
        float pm = p[mm];
#pragma unroll
        for (int d4 = 0; d4 < 8; ++d4) {
            float4 vv = vr[d4];
            oa[d4].x = fmaf(pm, vv.x, oa[d4].x);
            oa[d4].y = fmaf(pm, vv.y, oa[d4].y);
            oa[d4].z = fmaf(pm, vv.z, oa[d4].z);
            oa[d4].w = fmaf(pm, vv.w, oa[d4].w);
        }
    }
#pragma unroll
    for (int d4 = 0; d4 < 8; ++d4) {
        oa[d4].x += __shfl_xor(oa[d4].x, 1); oa[d4].x += __shfl_xor(oa[d4].x, 2);
        oa[d4].y += __shfl_xor(oa[d4].y, 1); oa[d4].y += __shfl_xor(oa[d4].y, 2);
        oa[d4].z += __shfl_xor(oa[d4].z, 1); oa[d4].z += __shfl_xor(oa[d4].z, 2);
        oa[d4].w += __shfl_xor(oa[d4].w, 1); oa[d4].w += __shfl_xor(oa[d4].w, 2);
    }
    float4 r0 = oa[sub * 2], r1 = oa[sub * 2 + 1];
    r0.x *= inv; r0.y *= inv; r0.z *= inv; r0.w *= inv;
    r1.x *= inv; r1.y *= inv; r1.z *= inv; r1.w *= inv;
    *(float4*)(OS + (size_t)bh * 2048 + g * 32 + sub * 8)     = r0;
    *(float4*)(OS + (size_t)bh * 2048 + g * 32 + sub * 8 + 4) = r1;
}

// ---------------- deslice: out_x = einsum(out_slice, sw) -> bf16 -----------
__global__ __launch_bounds__(256) void deslice_kernel(
    const float* __restrict__ OS, const u16* __restrict__ SW, u16* __restrict__ OX)
{
    __shared__ float swt[8 * 16 * 64];   // [hd][mm][g]
    int blk = blockIdx.x;
    int b = blk >> 10, n0 = (blk & 1023) * 16;
    int t = threadIdx.x;
    int hd = t >> 5, d = t & 31;
#pragma unroll
    for (int i = 0; i < 8; ++i) {
        int f4v = t + 256 * i;
        int hd2 = f4v >> 8, mm = (f4v >> 4) & 15, g4 = f4v & 15;
        ushort4 u = *(const ushort4*)(SW + (((size_t)(b * 8 + hd2)) * NB + n0 + mm) * 64 + g4 * 4);
        *(float4*)&swt[(hd2 * 16 + mm) * 64 + g4 * 4] = dec4(u);
    }
    __syncthreads();
    float acc[16];
#pragma unroll
    for (int mm = 0; mm < 16; ++mm) acc[mm] = 0.f;
    const float* osb = OS + ((size_t)(b * 8 + hd)) * 2048 + d;
#pragma unroll 4
    for (int g4 = 0; g4 < 16; ++g4) {
        float o0 = osb[(g4 * 4 + 0) * 32], o1 = osb[(g4 * 4 + 1) * 32];
        float o2 = osb[(g4 * 4 + 2) * 32], o3 = osb[(g4 * 4 + 3) * 32];
        const float* swp = swt + hd * 1024 + g4 * 4;
#pragma unroll
        for (int mm = 0; mm < 16; ++mm) {
            float4 sv = *(const float4*)(swp + mm * 64);
            acc[mm] = fmaf(o0, sv.x, fmaf(o1, sv.y, fmaf(o2, sv.z, fmaf(o3, sv.w, acc[mm]))));
        }
    }
#pragma unroll
    for (int mm = 0; mm < 16; ++mm)
        OX[((size_t)b * NB + n0 + mm) * 256 + t] = f2bf(acc[mm]);
}

// ---------------- head stage 2: out = hid @ head_w2 + b2 -------------------
__global__ __launch_bounds__(256) void head2_kernel(
    const u16* __restrict__ HID, const float* __restrict__ w2,
    const float* __restrict__ b2, const void* tmp, void* __restrict__ OUT)
{
    int isbf = (((const u16*)tmp)[0] != 0);
    int lane = threadIdx.x & 63;
    size_t m = (size_t)blockIdx.x * 4 + (threadIdx.x >> 6);
    const float4 hv = dec4(*(const ushort4*)(HID + m * 256 + lane * 4));
    float4 a = make_float4(0.f, 0.f, 0.f, 0.f);
    float hcomp[4] = {hv.x, hv.y, hv.z, hv.w};
#pragma unroll
    for (int i = 0; i < 4; ++i) {
        const float4 wv = *(const float4*)(w2 + (lane * 4 + i) * 4);
        float h = hcomp[i];
        a.x = fmaf(h, wv.x, a.x); a.y = fmaf(h, wv.y, a.y);
        a.z = fmaf(h, wv.z, a.z); a.w = fmaf(h, wv.w, a.w);
    }
#pragma unroll
    for (int o = 32; o; o >>= 1) {
        a.x += __shfl_xor(a.x, o); a.y += __shfl_xor(a.y, o);
        a.z += __shfl_xor(a.z, o); a.w += __shfl_xor(a.w, o);
    }
    if (lane == 0) {
        float o0 = a.x + b2[0], o1 = a.y + b2[1], o2 = a.z + b2[2], o3 = a.w + b2[3];
        if (isbf) {
            ushort4 r; r.x = f2bf(o0); r.y = f2bf(o1); r.z = f2bf(o2); r.w = f2bf(o3);
            *(ushort4*)((u16*)OUT + m * 4) = r;
        } else {
            *(float4*)((float*)OUT + m * 4) = make_float4(o0, o1, o2, o3);
        }
    }
}

// ---------------------------------------------------------------------------
extern "C" void kernel_launch(void* const* d_in, const int* in_sizes, int n_in,
                              void* d_out, int out_size, void* d_ws, size_t ws_size,
                              hipStream_t stream)
{
    const void* x = d_in[0];      const void* fx = d_in[1];
    const void* pre_w1 = d_in[2]; const void* pre_b1 = d_in[3];
    const void* pre_w2 = d_in[4]; const void* pre_b2 = d_in[5];
    const void* placeholder = d_in[6];
    const void* ln1_g = d_in[7];  const void* ln1_b = d_in[8];
    const void* px_w = d_in[9];   const void* px_b = d_in[10];
    const void* pfx_w = d_in[11]; const void* pfx_b = d_in[12];
    const void* slice_w = d_in[13]; const void* slice_b = d_in[14];
    const void* temp = d_in[15];
    const void* q_w = d_in[16];   const void* k_w = d_in[17]; const void* v_w = d_in[18];
    const void* out_w = d_in[19]; const void* out_b = d_in[20];
    const void* ln2_g = d_in[21]; const void* ln2_b = d_in[22];
    const void* mlp_w1 = d_in[23]; const void* mlp_b1 = d_in[24];
    const void* mlp_w2 = d_in[25]; const void* mlp_b2 = d_in[26];
    const void* ln3_g = d_in[27]; const void* ln3_b = d_in[28];
    const void* head_w1 = d_in[29]; const void* head_b1 = d_in[30];
    const void* head_w2 = d_in[31]; const void* head_b2 = d_in[32];

    float* ws = (float*)d_ws;
    u16*   Hb    = (u16*)(ws + F_H);   // bf16 residual stream
    float* OSp   = ws + F_OS;
    float* TOKP  = ws + F_TOKP;
    float* NORMP = ws + F_NORMP;
    float* TOKf  = ws + F_TOK;
    float* NORMf = ws + F_NORM;
    float* BIAS  = ws + F_BIAS;
    float* P     = ws + F_PARAMS;
    u16*   U     = (u16*)(ws + F_BF);
    u16*   WT    = U + U_WT;
    u16*   Yb    = U + U_Y;
    u16*   XMb   = U + U_XM;
    u16*   FMb   = U + U_FM;
    u16*   SWb   = U + U_SW;
    u16*   HIDb  = U + U_XM;   // [M,512] spans XM+FM (free before layer loop)

    cvt_kernel<<<910, 256, 0, stream>>>(x, fx, pre_w1, pre_b1, ln1_g, ln1_b,
        ln2_g, ln2_b, ln3_g, ln3_b, slice_w, slice_b, temp, q_w, k_w, v_w,
        head_w2, head_b2, P);
    prep_main<<<390, 256, 0, stream>>>(pre_w2, head_w1, pfx_w, out_w, mlp_w1,
        mlp_w2, pre_b2, placeholder, pfx_b, out_b, mlp_b1, mlp_b2, head_b1,
        temp, WT, BIAS);
    prep_pxsl<<<160, 256, 0, stream>>>(px_w, px_b, slice_w, slice_b, temp, WT, BIAS);
    pre1_kernel<<<8192, 256, 0, stream>>>(P, HIDb);

    dim3 gpl(256, 2);
    dim3 gsp(256, 6);
    // pre-MLP stage 2 + fused LN1[0]
    gemm_ln<512, false><<<512, 256, 0, stream>>>(HIDb, WT + WT_PRE2,
        BIAS + B_PB2C, P + P_LN1G, P + P_LN1B, Hb, Yb);

    for (int i = 0; i < 5; ++i) {
        gemm_spfx<<<gsp, 256, 0, stream>>>(Yb, WT + WT_SPFX + (size_t)i * 196608,
            BIAS + B_SP + i * 768, P + P_TEMP + i * 8, SWb, FMb);
        tok1_kernel<<<1024, 256, 0, stream>>>(FMb, SWb, TOKP, NORMP);
        tok2_kernel<<<132, 256, 0, stream>>>(TOKP, NORMP, TOKf, NORMf);
        attn_kernel<<<16, 256, 0, stream>>>(TOKf, NORMf, P + P_QW + i * 1024,
            P + P_KW + i * 1024, P + P_VW + i * 1024, OSp);
        deslice_kernel<<<2048, 256, 0, stream>>>(OSp, SWb, Yb);
        // out-proj + residual + fused LN2[i]
        gemm_ln<256, true><<<512, 256, 0, stream>>>(Yb, WT + WT_OUT + i * 65536,
            BIAS + B_OUTB + i * 256, P + P_LN2G + i * 256, P + P_LN2B + i * 256, Hb, Yb);
        // fused MLP: mlp1+gelu+mlp2 + residual + fused LN1[i+1] / LN3
        const float* ng = (i < 4) ? (P + P_LN1G + (i + 1) * 256) : (P + P_LN3G);
        const float* nb = (i < 4) ? (P + P_LN1B + (i + 1) * 256) : (P + P_LN3B);
        gemm_mlp<<<512, 256, 0, stream>>>(Yb, WT + WT_MLP1 + i * 65536,
            BIAS + B_M1B + i * 256, WT + WT_MLP2 + i * 65536,
            BIAS + B_M2B + i * 256, ng, nb, Hb, Yb);
    }

    gemm_gelu<<<gpl, 256, 0, stream>>>(Yb, WT + WT_HEAD1, BIAS + B_HB1, XMb);
    head2_kernel<<<8192, 256, 0, stream>>>(XMb, P + P_HW2, P + P_HB2, temp, d_out);
}

// Round 16
// 1029.668 us; speedup vs baseline: 1.1055x; 1.0148x over previous
//
#include <hip/hip_runtime.h>

// ---------------------------------------------------------------------------
// Transolver forward, MI355X. Round 16: R15 (verified 1045us) +
//  - prep_all: cvt + prep_main + prep_pxsl merged (independent work, one
//    1460-block kernel, shared LDS union)  [-2 dispatches]
//  - gemm_head: head1+head2 fused via the gemm_mlp skeleton (hidden in LDS,
//    K=256 dot with w2[256,4] in LDS)      [-1 dispatch, -32MB round-trip]
// ---------------------------------------------------------------------------

#define MTOK 32768   // B*N
#define NB   16384   // N

typedef unsigned short u16;
using short8 = __attribute__((ext_vector_type(8))) short;
using f4     = __attribute__((ext_vector_type(4))) float;

__device__ __forceinline__ float bfu(u16 u) {
    return __uint_as_float(((unsigned)u) << 16);
}
__device__ __forceinline__ u16 f2bf(float f) {
    unsigned u = __float_as_uint(f);
    u += 0x7FFFu + ((u >> 16) & 1u);   // round-to-nearest-even
    return (u16)(u >> 16);
}
__device__ __forceinline__ float ldf(const void* p, int i, int isbf) {
    return isbf ? bfu(((const u16*)p)[i]) : ((const float*)p)[i];
}
__device__ __forceinline__ float4 dec4(ushort4 u) {
    return make_float4(bfu(u.x), bfu(u.y), bfu(u.z), bfu(u.w));
}
__device__ __forceinline__ float gelu_f(float x) {
    return 0.5f * x * (1.0f + erff(x * 0.7071067811865475f));
}

typedef __attribute__((address_space(1))) const unsigned int* as1p;
typedef __attribute__((address_space(3))) unsigned int* as3p;
__device__ __forceinline__ void gload_lds16(const u16* g, u16* l) {
    __builtin_amdgcn_global_load_lds((as1p)g, (as3p)l, 16, 0, 0);
}

// ---------------- workspace layout -----------------------------------------
#define F_H      ((size_t)0)          // u16 H [32768,256] (in fp32 slot)
#define F_OS     ((size_t)8388608)    // [16,2048]
#define F_TOKP   ((size_t)8421376)    // [64ch,16bh,2048]
#define F_NORMP  ((size_t)10518528)   // [64ch,16bh,64]
#define F_TOK    ((size_t)10584064)   // [16,2048]
#define F_NORM   ((size_t)10616832)   // [16,64]
#define F_BIAS   ((size_t)10617856)
#define F_PARAMS ((size_t)10626048)   // fp32 small params (232836)
#define F_BF     ((size_t)10858884)   // u16 region base (byte off %16 == 0)
// bias-internal (floats, rel to F_BIAS)
#define B_PB2C 0        // 256
#define B_OUTB 256      // 1280
#define B_M1B  1536     // 1280
#define B_M2B  2816     // 1280
#define B_HB1  4096     // 256
#define B_SP   4352     // [5][768]: 0..511 folded slice bias, 512..767 pfx_b
#define B_END  8192
// u16 region offsets
#define U_WT     ((size_t)0)
#define WT_PRE2  0                   // [256][512]
#define WT_HEAD1 131072              // [256][256]
#define WT_SPFX  196608              // 5 x [768][256]: rows 0..511 pxsl, 512..767 pfx
#define WT_OUT   1179648             // 5 x [256][256]
#define WT_MLP1  1507328
#define WT_MLP2  1835008
#define WT_END   2162688
#define U_Y   ((size_t)2162688)      // [32768,256] bf16
#define U_XM  ((size_t)10551296)     // [32768,256]; +FM doubles as HID [32768,512]
#define U_FM  ((size_t)18939904)
#define U_SW  ((size_t)27328512)     // [16,16384,64]
// total ws: 10858884*4 + 44105728*2 = 131,646,992 B (~125.6 MB)

// params-internal offsets (floats, rel to F_PARAMS)
#define P_X    0
#define P_FX   65536
#define P_W1   196608
#define P_B1   199680
#define P_LN1G 200192
#define P_LN1B 201472
#define P_LN2G 202752
#define P_LN2B 204032
#define P_LN3G 205312
#define P_LN3B 205568
#define P_SLW  205824
#define P_SLB  216064
#define P_TEMP 216384
#define P_QW   216448
#define P_KW   221568
#define P_VW   226688
#define P_HW2  231808
#define P_HB2  232832
#define P_END  232836

// ---------------- prep_all: cvt + weight transpose + pxsl fold -------------
// blk<910: cvt small params; 910..1299: LDS-tiled transpose + biases;
// 1300..1459: pxsl fold. Branches are independent (cvt->P, rest->WT/BIAS).
__global__ __launch_bounds__(256) void prep_all(
    const void* x, const void* fx, const void* w1, const void* b1,
    const void* l1g, const void* l1b, const void* l2g, const void* l2b,
    const void* l3g, const void* l3b, const void* slw, const void* slb,
    const void* tmp, const void* qw, const void* kw, const void* vw,
    const void* hw2, const void* hb2,
    const void* pre_w2, const void* head_w1, const void* px_w, const void* px_b,
    const void* pfx_w, const void* out_w, const void* mlp_w1, const void* mlp_w2,
    const void* pre_b2, const void* placeholder, const void* pfx_b,
    const void* out_b, const void* mlp_b1, const void* mlp_b2, const void* head_b1,
    float* __restrict__ P, u16* __restrict__ WT, float* __restrict__ BIAS)
{
    __shared__ float shbuf[64 * 65];   // tile[64][65] OR pxs[2112]+sls[2048]
    int isbf = (((const u16*)tmp)[0] != 0);
    int blk = blockIdx.x;
    int t = threadIdx.x;
    if (blk < 910) {                              // ---- cvt ----
        int idx = blk * 256 + t;
        const void* s; int o;
        if      (idx < 65536)  { s = x;   o = idx; }
        else if (idx < 196608) { s = fx;  o = idx - 65536; }
        else if (idx < 199680) { s = w1;  o = idx - 196608; }
        else if (idx < 200192) { s = b1;  o = idx - 199680; }
        else if (idx < 201472) { s = l1g; o = idx - 200192; }
        else if (idx < 202752) { s = l1b; o = idx - 201472; }
        else if (idx < 204032) { s = l2g; o = idx - 202752; }
        else if (idx < 205312) { s = l2b; o = idx - 204032; }
        else if (idx < 205568) { s = l3g; o = idx - 205312; }
        else if (idx < 205824) { s = l3b; o = idx - 205568; }
        else if (idx < 216064) { s = slw; o = idx - 205824; }
        else if (idx < 216384) { s = slb; o = idx - 216064; }
        else if (idx < 216424) { s = tmp; o = idx - 216384; }
        else if (idx < 216448) { return; }
        else if (idx < 221568) { s = qw;  o = idx - 216448; }
        else if (idx < 226688) { s = kw;  o = idx - 221568; }
        else if (idx < 231808) { s = vw;  o = idx - 226688; }
        else if (idx < 232832) { s = hw2; o = idx - 231808; }
        else if (idx < 232836) { s = hb2; o = idx - 232832; }
        else return;
        P[idx] = ldf(s, o, isbf);
    } else if (blk < 1300) {                      // ---- transpose + biases ----
        int bb = blk - 910;
        if (bb < 368) {
            float (*tile)[65] = (float(*)[65])shbuf;
            const void* src; size_t srcoff; size_t dbase; int dstride;
            int k0, n0;
            if (bb < 32) {                        // pre_w2 [512,256] -> [256][512]
                int tk = bb >> 2, tn = bb & 3;
                src = pre_w2; srcoff = 0;
                k0 = tk * 64; n0 = tn * 64;
                dbase = WT_PRE2; dstride = 512;
            } else {
                int m = (bb - 32) >> 4, tl = (bb - 32) & 15;
                int tk = tl >> 2, tn = tl & 3;
                k0 = tk * 64; n0 = tn * 64; dstride = 256;
                if (m == 0)       { src = head_w1; srcoff = 0;               dbase = WT_HEAD1; }
                else if (m <= 5)  { int i = m - 1;  src = pfx_w;  srcoff = (size_t)i * 65536;
                                    dbase = WT_SPFX + (size_t)i * 196608 + (size_t)512 * 256; }
                else if (m <= 10) { int i = m - 6;  src = out_w;  srcoff = (size_t)i * 65536;
                                    dbase = WT_OUT + (size_t)i * 65536; }
                else if (m <= 15) { int i = m - 11; src = mlp_w1; srcoff = (size_t)i * 65536;
                                    dbase = WT_MLP1 + (size_t)i * 65536; }
                else              { int i = m - 16; src = mlp_w2; srcoff = (size_t)i * 65536;
                                    dbase = WT_MLP2 + (size_t)i * 65536; }
            }
#pragma unroll
            for (int p = 0; p < 16; ++p) {
                int flat = t + 256 * p;
                int r = flat >> 6, c = flat & 63;
                tile[r][c] = ldf(src, srcoff + (size_t)(k0 + r) * 256 + n0 + c, isbf);
            }
            __syncthreads();
#pragma unroll
            for (int p = 0; p < 16; ++p) {
                int flat = t + 256 * p;
                int r = flat >> 6, c = flat & 63;
                WT[dbase + (size_t)(n0 + r) * dstride + k0 + c] = f2bf(tile[c][r]);
            }
        } else {
            int idx = (bb - 368) * 256 + t;       // 0..5631
            if (idx < 256) {
                BIAS[B_PB2C + idx] = ldf(pre_b2, idx, isbf) + ldf(placeholder, idx, isbf);
            } else if (idx < 1536) {
                int o = idx - 256;  BIAS[B_OUTB + o] = ldf(out_b, o, isbf);
            } else if (idx < 2816) {
                int o = idx - 1536; BIAS[B_M1B + o] = ldf(mlp_b1, o, isbf);
            } else if (idx < 4096) {
                int o = idx - 2816; BIAS[B_M2B + o] = ldf(mlp_b2, o, isbf);
            } else if (idx < 4352) {
                int o = idx - 4096; BIAS[B_HB1 + o] = ldf(head_b1, o, isbf);
            } else if (idx < 5632) {
                int o = idx - 4352;
                int i = o >> 8, c = o & 255;
                BIAS[B_SP + i * 768 + 512 + c] = ldf(pfx_b, o, isbf);
            }
        }
    } else {                                      // ---- pxsl fold ----
        float* pxs = shbuf;                       // [64*33] = 2112
        float* sls = shbuf + 2112;                // [2048]
        int bb = blk - 1300;
        int i = bb >> 5, h = (bb >> 2) & 7, kb = bb & 3;
#pragma unroll
        for (int p = 0; p < 8; ++p) {
            int flat = t + 256 * p;
            sls[flat] = ldf(slw, i * 2048 + flat, isbf);
            int k = flat >> 5, d = flat & 31;
            pxs[k * 33 + d] = ldf(px_w, i * 65536 + (kb * 64 + k) * 256 + h * 32 + d, isbf);
        }
        __syncthreads();
        int k = t & 63, gb = t >> 6;
        float acc[16];
#pragma unroll
        for (int gi = 0; gi < 16; ++gi) acc[gi] = 0.f;
#pragma unroll
        for (int d = 0; d < 32; ++d) {
            float pv = pxs[k * 33 + d];
            const float* sp = sls + d * 64 + gb * 16;
#pragma unroll
            for (int gi = 0; gi < 16; ++gi) acc[gi] = fmaf(pv, sp[gi], acc[gi]);
        }
        u16* WTp = WT + WT_SPFX + (size_t)i * 196608;
#pragma unroll
        for (int gi = 0; gi < 16; ++gi) {
            int n = h * 64 + gb * 16 + gi;
            WTp[n * 256 + kb * 64 + k] = f2bf(acc[gi]);
        }
        if (kb == 0 && t < 64) {
            int g = t;
            float a = ldf(slb, i * 64 + g, isbf);
#pragma unroll
            for (int d = 0; d < 32; ++d)
                a = fmaf(ldf(px_b, i * 256 + h * 32 + d, isbf), sls[d * 64 + g], a);
            BIAS[B_SP + i * 768 + h * 64 + g] = a;
        }
    }
}

// ---------------- pre1: gelu(in6 @ pre_w1 + b1) -> bf16, conflict-free -----
__global__ __launch_bounds__(256) void pre1_kernel(
    const float* __restrict__ P, u16* __restrict__ HID)
{
    __shared__ float w1s[3072];
    __shared__ float b1s[512];
    int t = threadIdx.x;
#pragma unroll
    for (int p = 0; p < 12; ++p) w1s[t + 256 * p] = P[P_W1 + t + 256 * p];
    b1s[t] = P[P_B1 + t];
    b1s[t + 256] = P[P_B1 + t + 256];
    __syncthreads();
    int m = blockIdx.x * 4 + (t >> 6);
    int lane = t & 63;
    float xa = P[P_X + m * 2],      xb = P[P_X + m * 2 + 1];
    float fa = P[P_FX + m * 4],     fb = P[P_FX + m * 4 + 1];
    float fc = P[P_FX + m * 4 + 2], fd = P[P_FX + m * 4 + 3];
    size_t base = (size_t)m * 512 + lane;
#pragma unroll
    for (int jj = 0; jj < 8; ++jj) {
        int j = lane + 64 * jj;   // bank = lane%32 -> 2-way (free)
        float a = b1s[j];
        a = fmaf(xa, w1s[j], a);
        a = fmaf(xb, w1s[512 + j], a);
        a = fmaf(fa, w1s[1024 + j], a);
        a = fmaf(fb, w1s[1536 + j], a);
        a = fmaf(fc, w1s[2048 + j], a);
        a = fmaf(fd, w1s[2560 + j], a);
        HID[base + 64 * jj] = f2bf(gelu_f(a));
    }
}

// ---------------- LN-fused producer GEMM: 64x256, LDS-staged ---------------
template <int KK, bool RES>
__global__ __launch_bounds__(256, 3) void gemm_ln(
    const u16* __restrict__ A, const u16* __restrict__ Wt,
    const float* __restrict__ bias, const float* __restrict__ lng,
    const float* __restrict__ lnb, u16* __restrict__ Hb, u16* __restrict__ Y)
{
    __shared__ u16 As[64 * 64];
    __shared__ u16 Bs[256 * 64];
    __shared__ float rs2[2][64], rq2[2][64];
    const int t = threadIdx.x;
    const int wave = t >> 6, lane = t & 63;
    const int quad = lane >> 4, l15 = lane & 15;
    const int m0 = blockIdx.x * 64;
    const int wm = (wave & 1) * 32, wn = (wave >> 1) * 128;
    const int lrow = lane >> 3, ls = lane & 7;
    f4 acc[2][8];
#pragma unroll
    for (int i = 0; i < 2; ++i)
#pragma unroll
        for (int j = 0; j < 8; ++j) acc[i][j] = (f4){0.f, 0.f, 0.f, 0.f};

    for (int kc = 0; kc < KK; kc += 64) {
        if (kc) __syncthreads();
#pragma unroll
        for (int q = 0; q < 10; ++q) {
            int gr = wave * 80 + q * 8;
            if (gr < 64) {
                int row = gr + lrow;
                int chunk = ls ^ lrow;
                gload_lds16(A + (size_t)(m0 + row) * KK + kc + chunk * 8,
                            As + gr * 64);
            } else {
                int brow = gr - 64 + lrow;
                int chunk = ls ^ lrow;
                gload_lds16(Wt + (size_t)brow * KK + kc + chunk * 8,
                            Bs + (gr - 64) * 64);
            }
        }
        __syncthreads();
#pragma unroll
        for (int kk = 0; kk < 2; ++kk) {
            short8 a[2], b[8];
#pragma unroll
            for (int i = 0; i < 2; ++i) {
                int R = wm + i * 16 + l15;
                a[i] = *(const short8*)(As + R * 64 + (((quad + kk * 4) ^ (R & 7)) << 3));
            }
#pragma unroll
            for (int j = 0; j < 8; ++j) {
                int Rb = wn + j * 16 + l15;
                b[j] = *(const short8*)(Bs + Rb * 64 + (((quad + kk * 4) ^ (Rb & 7)) << 3));
            }
#pragma unroll
            for (int i = 0; i < 2; ++i)
#pragma unroll
                for (int j = 0; j < 8; ++j)
                    acc[i][j] = __builtin_amdgcn_mfma_f32_16x16x32_bf16(
                        a[i], b[j], acc[i][j], 0, 0, 0);
        }
    }
    int colj[8];
    float bj[8];
#pragma unroll
    for (int j = 0; j < 8; ++j) { colj[j] = wn + j * 16 + l15; bj[j] = bias[colj[j]]; }
    const int half = wn >> 7;
#pragma unroll
    for (int i = 0; i < 2; ++i) {
#pragma unroll
        for (int r = 0; r < 4; ++r) {
            int row = wm + i * 16 + quad * 4 + r;
            size_t gbase = (size_t)(m0 + row) * 256;
            float s = 0.f, q2 = 0.f;
#pragma unroll
            for (int j = 0; j < 8; ++j) {
                float v = acc[i][j][r] + bj[j];
                if (RES) v += bfu(Hb[gbase + colj[j]]);
                Hb[gbase + colj[j]] = f2bf(v);
                acc[i][j][r] = v;
                s += v; q2 += v * v;
            }
#pragma unroll
            for (int o = 1; o < 16; o <<= 1) { s += __shfl_xor(s, o); q2 += __shfl_xor(q2, o); }
            if (l15 == 0) { rs2[half][row] = s; rq2[half][row] = q2; }
        }
    }
    __syncthreads();
    float gj[8], betj[8];
#pragma unroll
    for (int j = 0; j < 8; ++j) { gj[j] = lng[colj[j]]; betj[j] = lnb[colj[j]]; }
#pragma unroll
    for (int i = 0; i < 2; ++i) {
#pragma unroll
        for (int r = 0; r < 4; ++r) {
            int row = wm + i * 16 + quad * 4 + r;
            size_t gbase = (size_t)(m0 + row) * 256;
            float mean = (rs2[0][row] + rs2[1][row]) * (1.0f / 256.0f);
            float var = (rq2[0][row] + rq2[1][row]) * (1.0f / 256.0f) - mean * mean;
            float rstd = rsqrtf(var + 1e-5f);
#pragma unroll
            for (int j = 0; j < 8; ++j) {
                float y = (acc[i][j][r] - mean) * rstd * gj[j] + betj[j];
                Y[gbase + colj[j]] = f2bf(y);
            }
        }
    }
}

// ---------------- fused MLP: gelu(Y@W1+b1)@W2+b2 + residual + LN -----------
// 64x256 full-row tile; hidden kept in LDS hs[64][264] (bf16, padded).
__global__ __launch_bounds__(256, 2) void gemm_mlp(
    const u16* __restrict__ A, const u16* __restrict__ W1,
    const float* __restrict__ b1, const u16* __restrict__ W2,
    const float* __restrict__ b2, const float* __restrict__ lng,
    const float* __restrict__ lnb, u16* __restrict__ Hb, u16* __restrict__ Y)
{
    __shared__ u16 As[64 * 64];
    __shared__ u16 Bs[256 * 64];
    __shared__ u16 hs[64 * 264];
    __shared__ float rs2[2][64], rq2[2][64];
    const int t = threadIdx.x;
    const int wave = t >> 6, lane = t & 63;
    const int quad = lane >> 4, l15 = lane & 15;
    const int m0 = blockIdx.x * 64;
    const int wm = (wave & 1) * 32, wn = (wave >> 1) * 128;
    const int lrow = lane >> 3, ls = lane & 7;
    f4 acc[2][8];
#pragma unroll
    for (int i = 0; i < 2; ++i)
#pragma unroll
        for (int j = 0; j < 8; ++j) acc[i][j] = (f4){0.f, 0.f, 0.f, 0.f};

    // ---- stage 1: hid = gelu(A @ W1 + b1) ----
    for (int kc = 0; kc < 256; kc += 64) {
        if (kc) __syncthreads();
#pragma unroll
        for (int q = 0; q < 10; ++q) {
            int gr = wave * 80 + q * 8;
            if (gr < 64) {
                int row = gr + lrow;
                gload_lds16(A + (size_t)(m0 + row) * 256 + kc + (ls ^ lrow) * 8,
                            As + gr * 64);
            } else {
                int brow = gr - 64 + lrow;
                gload_lds16(W1 + (size_t)brow * 256 + kc + (ls ^ lrow) * 8,
                            Bs + (gr - 64) * 64);
            }
        }
        __syncthreads();
#pragma unroll
        for (int kk = 0; kk < 2; ++kk) {
            short8 a[2], b[8];
#pragma unroll
            for (int i = 0; i < 2; ++i) {
                int R = wm + i * 16 + l15;
                a[i] = *(const short8*)(As + R * 64 + (((quad + kk * 4) ^ (R & 7)) << 3));
            }
#pragma unroll
            for (int j = 0; j < 8; ++j) {
                int Rb = wn + j * 16 + l15;
                b[j] = *(const short8*)(Bs + Rb * 64 + (((quad + kk * 4) ^ (Rb & 7)) << 3));
            }
#pragma unroll
            for (int i = 0; i < 2; ++i)
#pragma unroll
                for (int j = 0; j < 8; ++j)
                    acc[i][j] = __builtin_amdgcn_mfma_f32_16x16x32_bf16(
                        a[i], b[j], acc[i][j], 0, 0, 0);
        }
    }
    int colj[8];
#pragma unroll
    for (int j = 0; j < 8; ++j) colj[j] = wn + j * 16 + l15;
    {
        float bj[8];
#pragma unroll
        for (int j = 0; j < 8; ++j) bj[j] = b1[colj[j]];
#pragma unroll
        for (int i = 0; i < 2; ++i)
#pragma unroll
            for (int r = 0; r < 4; ++r) {
                int row = wm + i * 16 + quad * 4 + r;
#pragma unroll
                for (int j = 0; j < 8; ++j)
                    hs[row * 264 + colj[j]] = f2bf(gelu_f(acc[i][j][r] + bj[j]));
            }
    }
#pragma unroll
    for (int i = 0; i < 2; ++i)
#pragma unroll
        for (int j = 0; j < 8; ++j) acc[i][j] = (f4){0.f, 0.f, 0.f, 0.f};

    // ---- stage 2: out = hid @ W2 + b2 (+H residual) -> LN ----
    for (int kc = 0; kc < 256; kc += 64) {
        __syncthreads();   // protects Bs reuse + hs writes (1st iter)
#pragma unroll
        for (int q = 0; q < 8; ++q) {
            int gr = wave * 64 + q * 8;
            int brow = gr + lrow;
            gload_lds16(W2 + (size_t)brow * 256 + kc + (ls ^ lrow) * 8,
                        Bs + gr * 64);
        }
        __syncthreads();
#pragma unroll
        for (int kk = 0; kk < 2; ++kk) {
            short8 a[2], b[8];
#pragma unroll
            for (int i = 0; i < 2; ++i) {
                int R = wm + i * 16 + l15;
                a[i] = *(const short8*)(hs + R * 264 + kc + kk * 32 + quad * 8);
            }
#pragma unroll
            for (int j = 0; j < 8; ++j) {
                int Rb = wn + j * 16 + l15;
                b[j] = *(const short8*)(Bs + Rb * 64 + (((quad + kk * 4) ^ (Rb & 7)) << 3));
            }
#pragma unroll
            for (int i = 0; i < 2; ++i)
#pragma unroll
                for (int j = 0; j < 8; ++j)
                    acc[i][j] = __builtin_amdgcn_mfma_f32_16x16x32_bf16(
                        a[i], b[j], acc[i][j], 0, 0, 0);
        }
    }
    float bj[8];
#pragma unroll
    for (int j = 0; j < 8; ++j) bj[j] = b2[colj[j]];
    const int half = wn >> 7;
#pragma unroll
    for (int i = 0; i < 2; ++i) {
#pragma unroll
        for (int r = 0; r < 4; ++r) {
            int row = wm + i * 16 + quad * 4 + r;
            size_t gbase = (size_t)(m0 + row) * 256;
            float s = 0.f, q2 = 0.f;
#pragma unroll
            for (int j = 0; j < 8; ++j) {
                float v = acc[i][j][r] + bj[j] + bfu(Hb[gbase + colj[j]]);
                Hb[gbase + colj[j]] = f2bf(v);
                acc[i][j][r] = v;
                s += v; q2 += v * v;
            }
#pragma unroll
            for (int o = 1; o < 16; o <<= 1) { s += __shfl_xor(s, o); q2 += __shfl_xor(q2, o); }
            if (l15 == 0) { rs2[half][row] = s; rq2[half][row] = q2; }
        }
    }
    __syncthreads();
    float gj[8], betj[8];
#pragma unroll
    for (int j = 0; j < 8; ++j) { gj[j] = lng[colj[j]]; betj[j] = lnb[colj[j]]; }
#pragma unroll
    for (int i = 0; i < 2; ++i) {
#pragma unroll
        for (int r = 0; r < 4; ++r) {
            int row = wm + i * 16 + quad * 4 + r;
            size_t gbase = (size_t)(m0 + row) * 256;
            float mean = (rs2[0][row] + rs2[1][row]) * (1.0f / 256.0f);
            float var = (rq2[0][row] + rq2[1][row]) * (1.0f / 256.0f) - mean * mean;
            float rstd = rsqrtf(var + 1e-5f);
#pragma unroll
            for (int j = 0; j < 8; ++j) {
                float y = (acc[i][j][r] - mean) * rstd * gj[j] + betj[j];
                Y[gbase + colj[j]] = f2bf(y);
            }
        }
    }
}

// ---------------- fused head: gelu(Y@head_w1+b1) @ w2[256,4] + b2 ----------
// Stage 1 = gemm_mlp stage 1 (hidden -> LDS hs). Stage 2: per-thread K=256
// dot; thread t -> (row = t>>2, c = t&3); contiguous bf16/f32 stores.
__global__ __launch_bounds__(256, 2) void gemm_head(
    const u16* __restrict__ A, const u16* __restrict__ W1,
    const float* __restrict__ b1, const float* __restrict__ P,
    const void* tmp, void* __restrict__ OUT)
{
    __shared__ u16 As[64 * 64];
    __shared__ u16 Bs[256 * 64];
    __shared__ u16 hs[64 * 264];
    __shared__ float w2s[1024];
    const int t = threadIdx.x;
    const int wave = t >> 6, lane = t & 63;
    const int quad = lane >> 4, l15 = lane & 15;
    const int m0 = blockIdx.x * 64;
    const int wm = (wave & 1) * 32, wn = (wave >> 1) * 128;
    const int lrow = lane >> 3, ls = lane & 7;
#pragma unroll
    for (int p = 0; p < 4; ++p) w2s[t + 256 * p] = P[P_HW2 + t + 256 * p];
    f4 acc[2][8];
#pragma unroll
    for (int i = 0; i < 2; ++i)
#pragma unroll
        for (int j = 0; j < 8; ++j) acc[i][j] = (f4){0.f, 0.f, 0.f, 0.f};

    for (int kc = 0; kc < 256; kc += 64) {
        if (kc) __syncthreads();
#pragma unroll
        for (int q = 0; q < 10; ++q) {
            int gr = wave * 80 + q * 8;
            if (gr < 64) {
                int row = gr + lrow;
                gload_lds16(A + (size_t)(m0 + row) * 256 + kc + (ls ^ lrow) * 8,
                            As + gr * 64);
            } else {
                int brow = gr - 64 + lrow;
                gload_lds16(W1 + (size_t)brow * 256 + kc + (ls ^ lrow) * 8,
                            Bs + (gr - 64) * 64);
            }
        }
        __syncthreads();
#pragma unroll
        for (int kk = 0; kk < 2; ++kk) {
            short8 a[2], b[8];
#pragma unroll
            for (int i = 0; i < 2; ++i) {
                int R = wm + i * 16 + l15;
                a[i] = *(const short8*)(As + R * 64 + (((quad + kk * 4) ^ (R & 7)) << 3));
            }
#pragma unroll
            for (int j = 0; j < 8; ++j) {
                int Rb = wn + j * 16 + l15;
                b[j] = *(const short8*)(Bs + Rb * 64 + (((quad + kk * 4) ^ (Rb & 7)) << 3));
            }
#pragma unroll
            for (int i = 0; i < 2; ++i)
#pragma unroll
                for (int j = 0; j < 8; ++j)
                    acc[i][j] = __builtin_amdgcn_mfma_f32_16x16x32_bf16(
                        a[i], b[j], acc[i][j], 0, 0, 0);
        }
    }
    {
        float bj[8];
        int colj[8];
#pragma unroll
        for (int j = 0; j < 8; ++j) { colj[j] = wn + j * 16 + l15; bj[j] = b1[colj[j]]; }
#pragma unroll
        for (int i = 0; i < 2; ++i)
#pragma unroll
            for (int r = 0; r < 4; ++r) {
                int row = wm + i * 16 + quad * 4 + r;
#pragma unroll
                for (int j = 0; j < 8; ++j)
                    hs[row * 264 + colj[j]] = f2bf(gelu_f(acc[i][j][r] + bj[j]));
            }
    }
    __syncthreads();
    // ---- stage 2: out[m][c] = hs[row,:] . w2[:,c] + b2[c] ----
    int isbf = (((const u16*)tmp)[0] != 0);
    int row = t >> 2, c = t & 3;
    const u16* hrow = hs + row * 264;
    float a = 0.f;
#pragma unroll 8
    for (int k = 0; k < 256; ++k)
        a = fmaf(bfu(hrow[k]), w2s[k * 4 + c], a);
    a += P[P_HB2 + c];
    size_t off = (size_t)(m0 + row) * 4 + c;
    if (isbf) ((u16*)OUT)[off] = f2bf(a);
    else      ((float*)OUT)[off] = a;
}

// ---------------- merged slice+pfx GEMM: grid (256,6), LDS-staged ----------
__global__ __launch_bounds__(256, 4) void gemm_spfx(
    const u16* __restrict__ A, const u16* __restrict__ Wt,
    const float* __restrict__ bsp, const float* __restrict__ tempv,
    u16* __restrict__ SW, u16* __restrict__ FM)
{
    __shared__ u16 As[128 * 64];
    __shared__ u16 Bs[128 * 64];
    const int t = threadIdx.x;
    const int wave = t >> 6, lane = t & 63;
    const int quad = lane >> 4, l15 = lane & 15;
    const int m0 = blockIdx.x * 128;
    const int n0 = blockIdx.y * 128;
    const int wm = (wave & 1) * 64, wn = (wave >> 1) * 64;
    const int r0 = wave * 32;
    const int lrow = lane >> 3, ls = lane & 7;
    f4 acc[4][4];
#pragma unroll
    for (int i = 0; i < 4; ++i)
#pragma unroll
        for (int j = 0; j < 4; ++j) acc[i][j] = (f4){0.f, 0.f, 0.f, 0.f};

    for (int kc = 0; kc < 256; kc += 64) {
        if (kc) __syncthreads();
#pragma unroll
        for (int q = 0; q < 4; ++q) {
            int row = r0 + q * 8 + lrow;
            int chunk = ls ^ (row & 7);
            gload_lds16(A  + (size_t)(m0 + row) * 256 + kc + chunk * 8,
                        As + (r0 + q * 8) * 64);
            gload_lds16(Wt + (size_t)(n0 + row) * 256 + kc + chunk * 8,
                        Bs + (r0 + q * 8) * 64);
        }
        __syncthreads();
#pragma unroll
        for (int kk = 0; kk < 2; ++kk) {
            short8 a[4], b[4];
#pragma unroll
            for (int i = 0; i < 4; ++i) {
                int R = wm + i * 16 + l15;
                a[i] = *(const short8*)(As + R * 64 + (((quad + kk * 4) ^ (R & 7)) << 3));
            }
#pragma unroll
            for (int j = 0; j < 4; ++j) {
                int R = wn + j * 16 + l15;
                b[j] = *(const short8*)(Bs + R * 64 + (((quad + kk * 4) ^ (R & 7)) << 3));
            }
#pragma unroll
            for (int i = 0; i < 4; ++i)
#pragma unroll
                for (int j = 0; j < 4; ++j)
                    acc[i][j] = __builtin_amdgcn_mfma_f32_16x16x32_bf16(
                        a[i], b[j], acc[i][j], 0, 0, 0);
        }
    }
    float bj[4];
#pragma unroll
    for (int j = 0; j < 4; ++j) bj[j] = bsp[n0 + wn + j * 16 + l15];
    if (blockIdx.y < 4) {
        const int h = (n0 + wn) >> 6;
        const float itemp = 1.0f / tempv[h];
#pragma unroll
        for (int i = 0; i < 4; ++i) {
#pragma unroll
            for (int r = 0; r < 4; ++r) {
                float v[4];
                float mx = -3.0e38f;
#pragma unroll
                for (int j = 0; j < 4; ++j) {
                    v[j] = (acc[i][j][r] + bj[j]) * itemp;
                    mx = fmaxf(mx, v[j]);
                }
#pragma unroll
                for (int o = 1; o < 16; o <<= 1) mx = fmaxf(mx, __shfl_xor(mx, o));
                float s = 0.f;
#pragma unroll
                for (int j = 0; j < 4; ++j) { v[j] = expf(v[j] - mx); s += v[j]; }
#pragma unroll
                for (int o = 1; o < 16; o <<= 1) s += __shfl_xor(s, o);
                float inv = 1.0f / s;
                int m = m0 + wm + i * 16 + quad * 4 + r;
                int b = m >> 14, n = m & 16383;
                size_t base = (((size_t)(b * 8 + h)) * NB + n) * 64;
#pragma unroll
                for (int j = 0; j < 4; ++j)
                    SW[base + j * 16 + l15] = f2bf(v[j] * inv);
            }
        }
    } else {
        int cj = (n0 - 512) + wn + l15;
#pragma unroll
        for (int j = 0; j < 4; ++j) {
            int col = cj + j * 16;
#pragma unroll
            for (int i = 0; i < 4; ++i) {
                int rbase = m0 + wm + i * 16 + quad * 4;
#pragma unroll
                for (int r = 0; r < 4; ++r)
                    FM[(size_t)(rbase + r) * 256 + col] = f2bf(acc[i][j][r] + bj[j]);
            }
        }
    }
}

// ---------------- tok stage 1: per-chunk partials (64 chunks) --------------
__global__ __launch_bounds__(256) void tok1_kernel(
    const u16* __restrict__ FM, const u16* __restrict__ SW,
    float* __restrict__ TOKP, float* __restrict__ NORMP)
{
    int bh = blockIdx.x >> 6, chunk = blockIdx.x & 63;
    int b = bh >> 3, hd = bh & 7;
    int t = threadIdx.x, wave = t >> 6, lane = t & 63;
    int g0 = (lane >> 3) * 8, d0 = (lane & 7) * 4;
    float4 acc[8];
#pragma unroll
    for (int gi = 0; gi < 8; ++gi) acc[gi] = make_float4(0.f, 0.f, 0.f, 0.f);
    float4 n0a = make_float4(0.f, 0.f, 0.f, 0.f);
    float4 n1a = make_float4(0.f, 0.f, 0.f, 0.f);
    int nbase = chunk * 256 + wave * 64;
    const u16* fmB = FM + ((size_t)b * NB + nbase) * 256 + hd * 32 + d0;
    const u16* swB = SW + ((size_t)bh * NB + nbase) * 64 + g0;
    for (int j = 0; j < 64; ++j) {
        float4 f4v = dec4(*(const ushort4*)(fmB + (size_t)j * 256));
        float4 s0 = dec4(*(const ushort4*)(swB + (size_t)j * 64));
        float4 s1 = dec4(*(const ushort4*)(swB + (size_t)j * 64 + 4));
#define TOKACC(gi, sv)                                            \
        acc[gi].x = fmaf(f4v.x, sv, acc[gi].x);                   \
        acc[gi].y = fmaf(f4v.y, sv, acc[gi].y);                   \
        acc[gi].z = fmaf(f4v.z, sv, acc[gi].z);                   \
        acc[gi].w = fmaf(f4v.w, sv, acc[gi].w);
        TOKACC(0, s0.x) TOKACC(1, s0.y) TOKACC(2, s0.z) TOKACC(3, s0.w)
        TOKACC(4, s1.x) TOKACC(5, s1.y) TOKACC(6, s1.z) TOKACC(7, s1.w)
#undef TOKACC
        n0a.x += s0.x; n0a.y += s0.y; n0a.z += s0.z; n0a.w += s0.w;
        n1a.x += s1.x; n1a.y += s1.y; n1a.z += s1.z; n1a.w += s1.w;
    }
    __shared__ float red[4][2048];
    __shared__ float nred[4][64];
#pragma unroll
    for (int gi = 0; gi < 8; ++gi)
        *(float4*)&red[wave][(g0 + gi) * 32 + d0] = acc[gi];
    if ((lane & 7) == 0) {
        nred[wave][g0 + 0] = n0a.x; nred[wave][g0 + 1] = n0a.y;
        nred[wave][g0 + 2] = n0a.z; nred[wave][g0 + 3] = n0a.w;
        nred[wave][g0 + 4] = n1a.x; nred[wave][g0 + 5] = n1a.y;
        nred[wave][g0 + 6] = n1a.z; nred[wave][g0 + 7] = n1a.w;
    }
    __syncthreads();
    size_t tokBase = (size_t)(chunk * 16 + bh) * 2048;
#pragma unroll
    for (int k = 0; k < 8; ++k) {
        int c = t + 256 * k;
        TOKP[tokBase + c] = red[0][c] + red[1][c] + red[2][c] + red[3][c];
    }
    if (t < 64)
        NORMP[(chunk * 16 + bh) * 64 + t] = nred[0][t] + nred[1][t] + nred[2][t] + nred[3][t];
}

// ---------------- tok stage 2: parallel reduce over 64 chunks --------------
__global__ __launch_bounds__(256) void tok2_kernel(
    const float* __restrict__ TOKP, const float* __restrict__ NORMP,
    float* __restrict__ TOK, float* __restrict__ NORM)
{
    int idx = blockIdx.x * 256 + threadIdx.x;
    if (idx < 32768) {
        int bh = idx >> 11, c = idx & 2047;
        float s = 0.f;
#pragma unroll 8
        for (int ch = 0; ch < 64; ++ch) s += TOKP[(size_t)(ch * 16 + bh) * 2048 + c];
        TOK[idx] = s;
    } else if (idx < 33792) {
        int o = idx - 32768;
        int bh = o >> 6, g = o & 63;
        float s = 0.f;
#pragma unroll 8
        for (int ch = 0; ch < 64; ++ch) s += NORMP[(ch * 16 + bh) * 64 + g];
        NORM[o] = s;
    }
}

// ---------------- attention over G=64 tokens (block per (b,h)) -------------
__global__ __launch_bounds__(256) void attn_kernel(
    const float* __restrict__ TOK, const float* __restrict__ NORM,
    const float* __restrict__ qw, const float* __restrict__ kw,
    const float* __restrict__ vw, float* __restrict__ OS)
{
    __shared__ float tokd[2048], qs[2048], ks[2048], vs[2048];
    int bh = blockIdx.x;
    int t = threadIdx.x;
#pragma unroll
    for (int i = 0; i < 2; ++i) {
        int f4v = t + 256 * i;
        float4 v = *(const float4*)(TOK + (size_t)bh * 2048 + f4v * 4);
        float inv = 1.0f / (NORM[bh * 64 + (f4v >> 3)] + 1e-5f);
        v.x *= inv; v.y *= inv; v.z *= inv; v.w *= inv;
        *(float4*)&tokd[f4v * 4] = v;
    }
    __syncthreads();
#pragma unroll
    for (int i = 0; i < 8; ++i) {
        int f = t + 256 * i;
        int g = f >> 5, d = f & 31;
        const float* tr = tokd + g * 32;
        float aq = 0.f, ak = 0.f, av = 0.f;
#pragma unroll
        for (int e = 0; e < 32; ++e) {
            float tv = tr[e];
            aq = fmaf(tv, qw[e * 32 + d], aq);
            ak = fmaf(tv, kw[e * 32 + d], ak);
            av = fmaf(tv, vw[e * 32 + d], av);
        }
        qs[f] = aq; ks[f] = ak; vs[f] = av;
    }
    __syncthreads();
    int g = t >> 2, sub = t & 3;
    float4 qv[8];
#pragma unroll
    for (int e4 = 0; e4 < 8; ++e4) qv[e4] = *(const float4*)(qs + g * 32 + e4 * 4);
    float p[16];
    float mx = -3.0e38f;
#pragma unroll
    for (int mm = 0; mm < 16; ++mm) {
        int mI = sub * 16 + mm;
        const float4* kr = (const float4*)(ks + mI * 32);
        float s = 0.f;
#pragma unroll
        for (int e4 = 0; e4 < 8; ++e4) {
            float4 kv = kr[e4];
            s = fmaf(qv[e4].x, kv.x, s); s = fmaf(qv[e4].y, kv.y, s);
            s = fmaf(qv[e4].z, kv.z, s); s = fmaf(qv[e4].w, kv.w, s);
        }
        s *= 0.17677669529663687f;   // 1/sqrt(32)
        p[mm] = s;
        mx = fmaxf(mx, s);
    }
    mx = fmaxf(mx, __shfl_xor(mx, 1));
    mx = fmaxf(mx, __shfl_xor(mx, 2));
    float lsum = 0.f;
#pragma unroll
    for (int mm = 0; mm < 16; ++mm) { p[mm] = expf(p[mm] - mx); lsum += p[mm]; }
    lsum += __shfl_xor(lsum, 1);
    lsum += __shfl_xor(lsum, 2);
    float inv = 1.0f / lsum;
    float4 oa[8];
#pragma unroll
    for (int d4 = 0; d4 < 8; ++d4) oa[d4] = make_float4(0.f, 0.f, 0.f, 0.f);
#pragma unroll
    for (int mm = 0; mm < 16; ++mm) {
        int mI = sub * 16 + mm;
        const float4* vr = (const float4*)(vs + mI * 32);
        float pm = p[mm];
#pragma unroll
        for (int d4 = 0; d4 < 8; ++d4) {
            float4 vv = vr[d4];
            oa[d4].x = fmaf(pm, vv.x, oa[d4].x);
            oa[d4].y = fmaf(pm, vv.y, oa[d4].y);
            oa[d4].z = fmaf(pm, vv.z, oa[d4].z);
            oa[d4].w = fmaf(pm, vv.w, oa[d4].w);
        }
    }
#pragma unroll
    for (int d4 = 0; d4 < 8; ++d4) {
        oa[d4].x += __shfl_xor(oa[d4].x, 1); oa[d4].x += __shfl_xor(oa[d4].x, 2);
        oa[d4].y += __shfl_xor(oa[d4].y, 1); oa[d4].y += __shfl_xor(oa[d4].y, 2);
        oa[d4].z += __shfl_xor(oa[d4].z, 1); oa[d4].z += __shfl_xor(oa[d4].z, 2);
        oa[d4].w += __shfl_xor(oa[d4].w, 1); oa[d4].w += __shfl_xor(oa[d4].w, 2);
    }
    float4 r0 = oa[sub * 2], r1 = oa[sub * 2 + 1];
    r0.x *= inv; r0.y *= inv; r0.z *= inv; r0.w *= inv;
    r1.x *= inv; r1.y *= inv; r1.z *= inv; r1.w *= inv;
    *(float4*)(OS + (size_t)bh * 2048 + g * 32 + sub * 8)     = r0;
    *(float4*)(OS + (size_t)bh * 2048 + g * 32 + sub * 8 + 4) = r1;
}

// ---------------- deslice: out_x = einsum(out_slice, sw) -> bf16 -----------
__global__ __launch_bounds__(256) void deslice_kernel(
    const float* __restrict__ OS, const u16* __restrict__ SW, u16* __restrict__ OX)
{
    __shared__ float swt[8 * 16 * 64];   // [hd][mm][g]
    int blk = blockIdx.x;
    int b = blk >> 10, n0 = (blk & 1023) * 16;
    int t = threadIdx.x;
    int hd = t >> 5, d = t & 31;
#pragma unroll
    for (int i = 0; i < 8; ++i) {
        int f4v = t + 256 * i;
        int hd2 = f4v >> 8, mm = (f4v >> 4) & 15, g4 = f4v & 15;
        ushort4 u = *(const ushort4*)(SW + (((size_t)(b * 8 + hd2)) * NB + n0 + mm) * 64 + g4 * 4);
        *(float4*)&swt[(hd2 * 16 + mm) * 64 + g4 * 4] = dec4(u);
    }
    __syncthreads();
    float acc[16];
#pragma unroll
    for (int mm = 0; mm < 16; ++mm) acc[mm] = 0.f;
    const float* osb = OS + ((size_t)(b * 8 + hd)) * 2048 + d;
#pragma unroll 4
    for (int g4 = 0; g4 < 16; ++g4) {
        float o0 = osb[(g4 * 4 + 0) * 32], o1 = osb[(g4 * 4 + 1) * 32];
        float o2 = osb[(g4 * 4 + 2) * 32], o3 = osb[(g4 * 4 + 3) * 32];
        const float* swp = swt + hd * 1024 + g4 * 4;
#pragma unroll
        for (int mm = 0; mm < 16; ++mm) {
            float4 sv = *(const float4*)(swp + mm * 64);
            acc[mm] = fmaf(o0, sv.x, fmaf(o1, sv.y, fmaf(o2, sv.z, fmaf(o3, sv.w, acc[mm]))));
        }
    }
#pragma unroll
    for (int mm = 0; mm < 16; ++mm)
        OX[((size_t)b * NB + n0 + mm) * 256 + t] = f2bf(acc[mm]);
}

// ---------------------------------------------------------------------------
extern "C" void kernel_launch(void* const* d_in, const int* in_sizes, int n_in,
                              void* d_out, int out_size, void* d_ws, size_t ws_size,
                              hipStream_t stream)
{
    const void* x = d_in[0];      const void* fx = d_in[1];
    const void* pre_w1 = d_in[2]; const void* pre_b1 = d_in[3];
    const void* pre_w2 = d_in[4]; const void* pre_b2 = d_in[5];
    const void* placeholder = d_in[6];
    const void* ln1_g = d_in[7];  const void* ln1_b = d_in[8];
    const void* px_w = d_in[9];   const void* px_b = d_in[10];
    const void* pfx_w = d_in[11]; const void* pfx_b = d_in[12];
    const void* slice_w = d_in[13]; const void* slice_b = d_in[14];
    const void* temp = d_in[15];
    const void* q_w = d_in[16];   const void* k_w = d_in[17]; const void* v_w = d_in[18];
    const void* out_w = d_in[19]; const void* out_b = d_in[20];
    const void* ln2_g = d_in[21]; const void* ln2_b = d_in[22];
    const void* mlp_w1 = d_in[23]; const void* mlp_b1 = d_in[24];
    const void* mlp_w2 = d_in[25]; const void* mlp_b2 = d_in[26];
    const void* ln3_g = d_in[27]; const void* ln3_b = d_in[28];
    const void* head_w1 = d_in[29]; const void* head_b1 = d_in[30];
    const void* head_w2 = d_in[31]; const void* head_b2 = d_in[32];

    float* ws = (float*)d_ws;
    u16*   Hb    = (u16*)(ws + F_H);   // bf16 residual stream
    float* OSp   = ws + F_OS;
    float* TOKP  = ws + F_TOKP;
    float* NORMP = ws + F_NORMP;
    float* TOKf  = ws + F_TOK;
    float* NORMf = ws + F_NORM;
    float* BIAS  = ws + F_BIAS;
    float* P     = ws + F_PARAMS;
    u16*   U     = (u16*)(ws + F_BF);
    u16*   WT    = U + U_WT;
    u16*   Yb    = U + U_Y;
    u16*   FMb   = U + U_FM;
    u16*   SWb   = U + U_SW;
    u16*   HIDb  = U + U_XM;   // [M,512] spans XM+FM (free before layer loop)

    prep_all<<<1460, 256, 0, stream>>>(x, fx, pre_w1, pre_b1, ln1_g, ln1_b,
        ln2_g, ln2_b, ln3_g, ln3_b, slice_w, slice_b, temp, q_w, k_w, v_w,
        head_w2, head_b2,
        pre_w2, head_w1, px_w, px_b, pfx_w, out_w, mlp_w1, mlp_w2,
        pre_b2, placeholder, pfx_b, out_b, mlp_b1, mlp_b2, head_b1,
        P, WT, BIAS);
    pre1_kernel<<<8192, 256, 0, stream>>>(P, HIDb);

    dim3 gsp(256, 6);
    // pre-MLP stage 2 + fused LN1[0]
    gemm_ln<512, false><<<512, 256, 0, stream>>>(HIDb, WT + WT_PRE2,
        BIAS + B_PB2C, P + P_LN1G, P + P_LN1B, Hb, Yb);

    for (int i = 0; i < 5; ++i) {
        gemm_spfx<<<gsp, 256, 0, stream>>>(Yb, WT + WT_SPFX + (size_t)i * 196608,
            BIAS + B_SP + i * 768, P + P_TEMP + i * 8, SWb, FMb);
        tok1_kernel<<<1024, 256, 0, stream>>>(FMb, SWb, TOKP, NORMP);
        tok2_kernel<<<132, 256, 0, stream>>>(TOKP, NORMP, TOKf, NORMf);
        attn_kernel<<<16, 256, 0, stream>>>(TOKf, NORMf, P + P_QW + i * 1024,
            P + P_KW + i * 1024, P + P_VW + i * 1024, OSp);
        deslice_kernel<<<2048, 256, 0, stream>>>(OSp, SWb, Yb);
        // out-proj + residual + fused LN2[i]
        gemm_ln<256, true><<<512, 256, 0, stream>>>(Yb, WT + WT_OUT + i * 65536,
            BIAS + B_OUTB + i * 256, P + P_LN2G + i * 256, P + P_LN2B + i * 256, Hb, Yb);
        // fused MLP: mlp1+gelu+mlp2 + residual + fused LN1[i+1] / LN3
        const float* ng = (i < 4) ? (P + P_LN1G + (i + 1) * 256) : (P + P_LN3G);
        const float* nb = (i < 4) ? (P + P_LN1B + (i + 1) * 256) : (P + P_LN3B);
        gemm_mlp<<<512, 256, 0, stream>>>(Yb, WT + WT_MLP1 + i * 65536,
            BIAS + B_M1B + i * 256, WT + WT_MLP2 + i * 65536,
            BIAS + B_M2B + i * 256, ng, nb, Hb, Yb);
    }

    // fused head: head1 + gelu + head2 -> output
    gemm_head<<<512, 256, 0, stream>>>(Yb, WT + WT_HEAD1, BIAS + B_HB1,
        P, temp, d_out);
}